// Round 13
// baseline (151.501 us; speedup 1.0000x reference)
//
#include <hip/hip_runtime.h>
#include <hip/hip_bf16.h>

// Shapes (fixed): B=2, S=2048, E=1024, H=16, D=64
// d_out: out[4194304] fp32 | k[4194304] fp32 [B,H,S,D] | v[4194304] fp32 [B,H,S,D]
// ws: x_bf | wT1 | wT2 | q_bf | k_bf | vT_bf ; o_bf aliases x_bf.

typedef __attribute__((ext_vector_type(4))) float f32x4;
typedef __attribute__((ext_vector_type(16))) float f32x16;
typedef __attribute__((ext_vector_type(8))) short s16x8;
typedef __attribute__((ext_vector_type(4))) short s16x4;

__device__ __forceinline__ short f2bf(float f) {
    union { float f; unsigned u; } x{f};
    unsigned r = x.u + 0x7fff + ((x.u >> 16) & 1);
    return (short)(r >> 16);
}

__device__ __forceinline__ void gload_lds16(const void* g, void* l) {
    __builtin_amdgcn_global_load_lds(
        (const __attribute__((address_space(1))) void*)g,
        (__attribute__((address_space(3))) void*)l, 16, 0, 0);
}

// ---------------- pre-pass kernels ----------------

__global__ __launch_bounds__(256) void convert_f32_bf16(const float* __restrict__ in,
                                                        short* __restrict__ out, int n) {
    int i = (blockIdx.x * 256 + threadIdx.x) * 8;
    if (i + 7 < n) {
        f32x4 a = *(const f32x4*)&in[i];
        f32x4 b = *(const f32x4*)&in[i + 4];
        s16x8 o;
        #pragma unroll
        for (int j = 0; j < 4; ++j) o[j] = f2bf(a[j]);
        #pragma unroll
        for (int j = 0; j < 4; ++j) o[j + 4] = f2bf(b[j]);
        *(s16x8*)&out[i] = o;
    }
}

// in: [K][N] fp32 row-major -> out: [N][K] bf16 row-major
__global__ __launch_bounds__(256) void transpose_conv(const float* __restrict__ in,
                                                      short* __restrict__ out, int K, int N) {
    __shared__ float tile[32][33];
    int tx = threadIdx.x, ty = threadIdx.y;  // 32 x 8
    int n0 = blockIdx.x * 32, k0 = blockIdx.y * 32;
    #pragma unroll
    for (int r = 0; r < 4; ++r)
        tile[ty + r * 8][tx] = in[(long)(k0 + ty + r * 8) * N + n0 + tx];
    __syncthreads();
    #pragma unroll
    for (int r = 0; r < 4; ++r)
        out[(long)(n0 + ty + r * 8) * K + k0 + tx] = f2bf(tile[tx][ty + r * 8]);
}

// vout fp32 [32][2048][64] (in d_out) -> vT_bf [32][64][2048] bf16, coalesced both sides
__global__ __launch_bounds__(256) void transpose_v(const float* __restrict__ vin,
                                                   short* __restrict__ vT) {
    __shared__ float tile[32][33];
    const int bh = blockIdx.z;
    const int s0 = blockIdx.x * 32, d0 = blockIdx.y * 32;
    const int tx = threadIdx.x, ty = threadIdx.y;  // 32 x 8
    const float* src = vin + (long)bh * 2048 * 64;
    short* dst = vT + (long)bh * 64 * 2048;
    #pragma unroll
    for (int r = 0; r < 4; ++r)
        tile[ty + r * 8][tx] = src[(long)(s0 + ty + r * 8) * 64 + d0 + tx];
    __syncthreads();
    #pragma unroll
    for (int r = 0; r < 4; ++r)
        dst[(long)(d0 + ty + r * 8) * 2048 + s0 + tx] = f2bf(tile[tx][ty + r * 8]);
}

// ---------------- GEMM (m97-style: 128x128 tile, BK=32, global_load_lds) ----------------
// A: [M][K] bf16, Bt: [N][K] bf16.  MODE 1: qkv epilogue. MODE 2: plain bias epilogue.

template <int MODE>
__global__ __launch_bounds__(256) void gemm_bf16(
    const short* __restrict__ A, const short* __restrict__ Bt,
    const float* __restrict__ bias, int M, int N, int K,
    float* __restrict__ outf,
    short* __restrict__ qbf, short* __restrict__ kbf,
    float* __restrict__ kout, float* __restrict__ vout) {
    __shared__ __align__(16) short As[128 * 32];
    __shared__ __align__(16) short Bs[128 * 32];
    const int tid = threadIdx.x;
    const int l = tid & 63, w = tid >> 6;
    const int lr = l >> 4, lc = l & 15;
    const int wm = w >> 1, wn = w & 1;
    const int m0 = blockIdx.y * 128, n0 = blockIdx.x * 128;

    f32x4 acc[4][4] = {};
    const int c0 = tid, c1 = tid + 256;  // 16B chunks; chunk c -> row c>>2, seg c&3

    for (int kb = 0; kb < K; kb += 32) {
        __syncthreads();
        gload_lds16(A + (long)(m0 + (c0 >> 2)) * K + kb + (c0 & 3) * 8, As + c0 * 8);
        gload_lds16(A + (long)(m0 + (c1 >> 2)) * K + kb + (c1 & 3) * 8, As + c1 * 8);
        gload_lds16(Bt + (long)(n0 + (c0 >> 2)) * K + kb + (c0 & 3) * 8, Bs + c0 * 8);
        gload_lds16(Bt + (long)(n0 + (c1 >> 2)) * K + kb + (c1 & 3) * 8, Bs + c1 * 8);
        __syncthreads();
        s16x8 af[4], bfr[4];
        #pragma unroll
        for (int mi = 0; mi < 4; ++mi)
            af[mi] = *(const s16x8*)&As[(wm * 64 + mi * 16 + lc) * 32 + lr * 8];
        #pragma unroll
        for (int ni = 0; ni < 4; ++ni)
            bfr[ni] = *(const s16x8*)&Bs[(wn * 64 + ni * 16 + lc) * 32 + lr * 8];
        #pragma unroll
        for (int mi = 0; mi < 4; ++mi)
            #pragma unroll
            for (int ni = 0; ni < 4; ++ni)
                acc[mi][ni] = __builtin_amdgcn_mfma_f32_16x16x32_bf16(
                    af[mi], bfr[ni], acc[mi][ni], 0, 0, 0);
    }

    #pragma unroll
    for (int mi = 0; mi < 4; ++mi) {
        #pragma unroll
        for (int ni = 0; ni < 4; ++ni) {
            int col = n0 + wn * 64 + ni * 16 + lc;
            float bv = bias[col];
            if (MODE == 1) {
                int sec = col >> 10, rem = col & 1023;
                int h = rem >> 6, d = rem & 63;
                int row0 = m0 + wm * 64 + mi * 16 + lr * 4;
                int b = row0 >> 11, s0 = row0 & 2047;
                long idxSD = ((long)((b << 4) + h) * 2048 + s0) * 64 + d;
                if (sec == 0) {
                    #pragma unroll
                    for (int i = 0; i < 4; ++i) {
                        float val = acc[mi][ni][i] + bv;
                        // bake attn scale 1/8 and log2(e) for exp2-domain softmax
                        qbf[idxSD + (long)i * 64] = f2bf(val * 0.1803368801111244f);
                    }
                } else if (sec == 1) {
                    #pragma unroll
                    for (int i = 0; i < 4; ++i) {
                        float val = acc[mi][ni][i] + bv;
                        kout[idxSD + (long)i * 64] = val;
                        kbf[idxSD + (long)i * 64] = f2bf(val);
                    }
                } else {
                    #pragma unroll
                    for (int i = 0; i < 4; ++i) {
                        float val = acc[mi][ni][i] + bv;
                        vout[idxSD + (long)i * 64] = val;  // fp32 V out; vT_bf made by transpose_v
                    }
                }
            } else {
                #pragma unroll
                for (int i = 0; i < 4; ++i) {
                    int row = m0 + wm * 64 + mi * 16 + lr * 4 + i;
                    outf[(long)row * N + col] = acc[mi][ni][i] + bv;
                }
            }
        }
    }
}

// ---------------- flash attention (32x32 MFMA, 2-wave blocks, full co-residency) -------
// grid: 1024 blocks = 32 bh x 32 q-tiles of 64 rows; 128 threads (2 waves x 32 q-rows).
// 32 KB LDS/block -> 5 blocks/CU capacity; ALL 1024 blocks co-resident (4/CU = 8 waves/CU)
// from t=0, so every block always has ~3 other blocks' waves to overlap its serial chain
// (round-12 lesson: complementary pairing left CUs running ONE 4-wave barrier-locked block
// for most of the kernel -> 3700 cyc/step exposed chain).
// qt descending in slot so deepest blocks (nkt = qt+1 = 32) start first.
// Per 64-key step: block stages K [64k][64d] + V^T [64d][64k] once (global_load_lds w16,
// double-buffered, chunk XOR-swizzle both-sides; wave wv stages rows wv*32..+31).
// 32x32x16 MFMAs; C-layout col q = lane&31, row = (r&3)+8*(r>>2)+4*(lane>>5).
// P stays IN REGISTERS via kdim permutation pi (round 12, verified): B = f2bf-pack of own
// p[8] in order; A (V^T) = two ds_read_b64 at k = fb+4h, fb+8+4h.
// STATIC softmax: p = exp2(s'), no max-tracking (causal rows contain the diagonal).
__global__ __launch_bounds__(128, 2) void attn_kernel(const short* __restrict__ qbf,
                                                      const short* __restrict__ kbf,
                                                      const short* __restrict__ vbfT,
                                                      short* __restrict__ obf) {
    const int bid = blockIdx.x;
    const int xcd = bid & 7, slot = bid >> 3;   // 128 slots per XCD
    const int head_local = slot >> 5;           // 4 heads per XCD (K/V L2-resident)
    const int qt = 31 - (slot & 31);            // qt descending: deep blocks first
    const int bh = xcd * 4 + head_local;
    const int tid = threadIdx.x;
    const int wv = tid >> 6, l = tid & 63;      // wv in 0..1
    const int h = l >> 5;                        // lane half
    const int l8 = l & 7;
    const int q0 = qt * 64 + wv * 32;            // this wave's 32-q strip
    const int qlane = q0 + (l & 31);
    const long baseSD = (long)bh * 2048 * 64;   // q,k: [S][64]
    const long baseDS = (long)bh * 64 * 2048;   // vT:  [64][S]

    __shared__ __align__(16) short Ks[2][64 * 64];  // swizzled K tile   (8 KB x2)
    __shared__ __align__(16) short Vs[2][64 * 64];  // swizzled V^T tile (8 KB x2)

    // staging: wave wv stages rows wv*32..wv*32+31 (4 chunks of 8 rows each);
    // lane l -> row base+(l>>3), phys chunk l&7 holds logical chunk (l&7)^(l>>3).
    const int sSub = l >> 3;
    const int sChunk = (l & 7) ^ sSub;
    auto stage = [&](int kt, int nb) {
        const int k0 = kt * 64;
        const int r0 = wv * 32 + sSub;
        #pragma unroll
        for (int rr = 0; rr < 4; ++rr) {
            gload_lds16(kbf + baseSD + (long)(k0 + r0 + rr * 8) * 64 + sChunk * 8,
                        &Ks[nb][(wv * 32 + rr * 8) * 64]);
            gload_lds16(vbfT + baseDS + (long)(r0 + rr * 8) * 2048 + k0 + sChunk * 8,
                        &Vs[nb][(wv * 32 + rr * 8) * 64]);
        }
    };

    // Q fragments (B-operand, 32x32x16): lane holds col q = qlane, kdim d = dd*16 + h*8 + j
    s16x8 qf[4];
    #pragma unroll
    for (int dd = 0; dd < 4; ++dd)
        qf[dd] = *(const s16x8*)&qbf[baseSD + (long)qlane * 64 + dd * 16 + h * 8];

    float lsum = 0.f;                  // per-lane PARTIAL sum over this lane's k-subset
    f32x16 O[2] = {};                  // O^T: O[dt2][rr] = O[d = dt2*32+(rr&3)+8*(rr>>2)+4h][qlane]

    const int nkt = qt + 1;            // k-tiles covering keys 0..qt*64+63

    stage(0, 0);
    __syncthreads();                   // drains vmcnt -> buf0 ready
    int cur = 0;

    for (int kt = 0; kt < nkt; ++kt) {
        const int k0 = kt * 64;
        if (kt + 1 < nkt) stage(kt + 1, cur ^ 1);

        if (k0 <= q0 + 31) {           // strip has unmasked keys in this tile
            const short* Kb = Ks[cur];
            const short* Vb = Vs[cur];
            #pragma unroll
            for (int kk2 = 0; kk2 < 2; ++kk2) {
                // QK: S^T[32k x 32q] accumulated over d
                f32x16 z = {};
                #pragma unroll
                for (int dd = 0; dd < 4; ++dd) {
                    s16x8 kf = *(const s16x8*)&Kb[(kk2 * 32 + (l & 31)) * 64 +
                                                  (((2 * dd + h) ^ l8) * 8)];
                    z = __builtin_amdgcn_mfma_f32_32x32x16_bf16(kf, qf[dd], z, 0, 0, 0);
                }
                // causal mask: k = k0 + kk2*32 + (rr&3)+8*(rr>>2)+4h, q = qlane
                if (k0 + 63 > q0) {
                    #pragma unroll
                    for (int rr = 0; rr < 16; ++rr) {
                        int kpos = k0 + kk2 * 32 + (rr & 3) + 8 * (rr >> 2) + 4 * h;
                        if (kpos > qlane) z[rr] = -INFINITY;
                    }
                }
                // static softmax: p = exp2(s'); exp2(-inf) = 0 handles the mask
                float p[16];
                #pragma unroll
                for (int rr = 0; rr < 16; ++rr) {
                    p[rr] = __builtin_amdgcn_exp2f(z[rr]);
                    lsum += p[rr];
                }
                // PV per 16-k fragment f (k base fb = kk2*32 + f*16), pi-permuted kdim:
                //   B = pack of own p[f*8..f*8+7] (f2bf, in order);
                //   A = V^T rows, two b64 at k = fb+4h and fb+8+4h.
                #pragma unroll
                for (int f = 0; f < 2; ++f) {
                    s16x8 pf;
                    #pragma unroll
                    for (int j = 0; j < 8; ++j) pf[j] = f2bf(p[f * 8 + j]);
                    const int c0 = kk2 * 4 + f * 2;       // logical chunk of fb
                    #pragma unroll
                    for (int dt2 = 0; dt2 < 2; ++dt2) {
                        const short* vr = &Vb[(dt2 * 32 + (l & 31)) * 64];
                        s16x8 vf;
                        *(s16x4*)&vf = *(const s16x4*)&vr[(c0 ^ l8) * 8 + 4 * h];
                        *(((s16x4*)&vf) + 1) = *(const s16x4*)&vr[((c0 + 1) ^ l8) * 8 + 4 * h];
                        O[dt2] = __builtin_amdgcn_mfma_f32_32x32x16_bf16(vf, pf,
                                                                         O[dt2], 0, 0, 0);
                    }
                }
            }
        }
        __syncthreads();               // all done with buf[cur]; stage(kt+1) drained
        cur ^= 1;
    }

    // epilogue: merge lane halves' partial lsum (1 shuffle), O /= lsum; packed 8B stores
    lsum += __shfl_xor(lsum, 32);
    const int b = bh >> 4, hd = bh & 15;
    float inv = 1.0f / lsum;
    #pragma unroll
    for (int dt2 = 0; dt2 < 2; ++dt2) {
        #pragma unroll
        for (int g = 0; g < 4; ++g) {
            s16x4 o;
            #pragma unroll
            for (int i = 0; i < 4; ++i) o[i] = f2bf(O[dt2][g * 4 + i] * inv);
            const int d = dt2 * 32 + 8 * g + 4 * h;
            *(s16x4*)&obf[(long)(b * 2048 + qlane) * 1024 + hd * 64 + d] = o;
        }
    }
}

// ---------------- launch ----------------

extern "C" void kernel_launch(void* const* d_in, const int* in_sizes, int n_in,
                              void* d_out, int out_size, void* d_ws, size_t ws_size,
                              hipStream_t stream) {
    const float* x = (const float*)d_in[0];
    const float* qkv_w = (const float*)d_in[1];
    const float* qkv_b = (const float*)d_in[2];
    const float* proj_w = (const float*)d_in[3];
    const float* proj_b = (const float*)d_in[4];

    float* out = (float*)d_out;
    float* kout = out + 4194304;
    float* vout = out + 8388608;

    short* x_bf = (short*)d_ws;           // 4194304 shorts
    short* wT1 = x_bf + 4194304;          // 3145728
    short* wT2 = wT1 + 3145728;           // 1048576
    short* q_bf = wT2 + 1048576;          // 4194304
    short* k_bf = q_bf + 4194304;         // 4194304
    short* vT_bf = k_bf + 4194304;        // 4194304 ([B,H,D,S])
    short* o_bf = x_bf;                   // alias: x_bf dead after GEMM1

    convert_f32_bf16<<<2048, 256, 0, stream>>>(x, x_bf, 4194304);
    transpose_conv<<<dim3(96, 32), dim3(32, 8), 0, stream>>>(qkv_w, wT1, 1024, 3072);
    transpose_conv<<<dim3(32, 32), dim3(32, 8), 0, stream>>>(proj_w, wT2, 1024, 1024);

    gemm_bf16<1><<<dim3(24, 32), 256, 0, stream>>>(x_bf, wT1, qkv_b, 4096, 3072, 1024,
                                                   nullptr, q_bf, k_bf, kout, vout);

    transpose_v<<<dim3(64, 2, 32), dim3(32, 8), 0, stream>>>(vout, vT_bf);

    attn_kernel<<<1024, 128, 0, stream>>>(q_bf, k_bf, vT_bf, o_bf);

    gemm_bf16<2><<<dim3(8, 32), 256, 0, stream>>>(o_bf, wT2, proj_b, 4096, 1024, 1024,
                                                  out, nullptr, nullptr, nullptr, nullptr);
}

// Round 14
// 137.339 us; speedup vs baseline: 1.1031x; 1.1031x over previous
//
#include <hip/hip_runtime.h>
#include <hip/hip_bf16.h>

// Shapes (fixed): B=2, S=2048, E=1024, H=16, D=64
// d_out: out[4194304] fp32 | k[4194304] fp32 [B,H,S,D] | v[4194304] fp32 [B,H,S,D]
// ws: x_bf | wT1 | wT2 | q_bf | k_bf | vT_bf ; o_bf aliases x_bf.

typedef __attribute__((ext_vector_type(4))) float f32x4;
typedef __attribute__((ext_vector_type(16))) float f32x16;
typedef __attribute__((ext_vector_type(8))) short s16x8;
typedef __attribute__((ext_vector_type(4))) short s16x4;

__device__ __forceinline__ short f2bf(float f) {
    union { float f; unsigned u; } x{f};
    unsigned r = x.u + 0x7fff + ((x.u >> 16) & 1);
    return (short)(r >> 16);
}

__device__ __forceinline__ void gload_lds16(const void* g, void* l) {
    __builtin_amdgcn_global_load_lds(
        (const __attribute__((address_space(1))) void*)g,
        (__attribute__((address_space(3))) void*)l, 16, 0, 0);
}

// ---------------- pre-pass kernels ----------------

__global__ __launch_bounds__(256) void convert_f32_bf16(const float* __restrict__ in,
                                                        short* __restrict__ out, int n) {
    int i = (blockIdx.x * 256 + threadIdx.x) * 8;
    if (i + 7 < n) {
        f32x4 a = *(const f32x4*)&in[i];
        f32x4 b = *(const f32x4*)&in[i + 4];
        s16x8 o;
        #pragma unroll
        for (int j = 0; j < 4; ++j) o[j] = f2bf(a[j]);
        #pragma unroll
        for (int j = 0; j < 4; ++j) o[j + 4] = f2bf(b[j]);
        *(s16x8*)&out[i] = o;
    }
}

// in: [K][N] fp32 row-major -> out: [N][K] bf16 row-major
__global__ __launch_bounds__(256) void transpose_conv(const float* __restrict__ in,
                                                      short* __restrict__ out, int K, int N) {
    __shared__ float tile[32][33];
    int tx = threadIdx.x, ty = threadIdx.y;  // 32 x 8
    int n0 = blockIdx.x * 32, k0 = blockIdx.y * 32;
    #pragma unroll
    for (int r = 0; r < 4; ++r)
        tile[ty + r * 8][tx] = in[(long)(k0 + ty + r * 8) * N + n0 + tx];
    __syncthreads();
    #pragma unroll
    for (int r = 0; r < 4; ++r)
        out[(long)(n0 + ty + r * 8) * K + k0 + tx] = f2bf(tile[tx][ty + r * 8]);
}

// vout fp32 [32][2048][64] (in d_out) -> vT_bf [32][64][2048] bf16, coalesced both sides
__global__ __launch_bounds__(256) void transpose_v(const float* __restrict__ vin,
                                                   short* __restrict__ vT) {
    __shared__ float tile[32][33];
    const int bh = blockIdx.z;
    const int s0 = blockIdx.x * 32, d0 = blockIdx.y * 32;
    const int tx = threadIdx.x, ty = threadIdx.y;  // 32 x 8
    const float* src = vin + (long)bh * 2048 * 64;
    short* dst = vT + (long)bh * 64 * 2048;
    #pragma unroll
    for (int r = 0; r < 4; ++r)
        tile[ty + r * 8][tx] = src[(long)(s0 + ty + r * 8) * 64 + d0 + tx];
    __syncthreads();
    #pragma unroll
    for (int r = 0; r < 4; ++r)
        dst[(long)(d0 + ty + r * 8) * 2048 + s0 + tx] = f2bf(tile[tx][ty + r * 8]);
}

// ---------------- GEMM (m97-style: 128x128 tile, BK=32, global_load_lds) ----------------
// A: [M][K] bf16, Bt: [N][K] bf16.  MODE 1: qkv epilogue. MODE 2: plain bias epilogue.

template <int MODE>
__global__ __launch_bounds__(256) void gemm_bf16(
    const short* __restrict__ A, const short* __restrict__ Bt,
    const float* __restrict__ bias, int M, int N, int K,
    float* __restrict__ outf,
    short* __restrict__ qbf, short* __restrict__ kbf,
    float* __restrict__ kout, float* __restrict__ vout) {
    __shared__ __align__(16) short As[128 * 32];
    __shared__ __align__(16) short Bs[128 * 32];
    const int tid = threadIdx.x;
    const int l = tid & 63, w = tid >> 6;
    const int lr = l >> 4, lc = l & 15;
    const int wm = w >> 1, wn = w & 1;
    const int m0 = blockIdx.y * 128, n0 = blockIdx.x * 128;

    f32x4 acc[4][4] = {};
    const int c0 = tid, c1 = tid + 256;  // 16B chunks; chunk c -> row c>>2, seg c&3

    for (int kb = 0; kb < K; kb += 32) {
        __syncthreads();
        gload_lds16(A + (long)(m0 + (c0 >> 2)) * K + kb + (c0 & 3) * 8, As + c0 * 8);
        gload_lds16(A + (long)(m0 + (c1 >> 2)) * K + kb + (c1 & 3) * 8, As + c1 * 8);
        gload_lds16(Bt + (long)(n0 + (c0 >> 2)) * K + kb + (c0 & 3) * 8, Bs + c0 * 8);
        gload_lds16(Bt + (long)(n0 + (c1 >> 2)) * K + kb + (c1 & 3) * 8, Bs + c1 * 8);
        __syncthreads();
        s16x8 af[4], bfr[4];
        #pragma unroll
        for (int mi = 0; mi < 4; ++mi)
            af[mi] = *(const s16x8*)&As[(wm * 64 + mi * 16 + lc) * 32 + lr * 8];
        #pragma unroll
        for (int ni = 0; ni < 4; ++ni)
            bfr[ni] = *(const s16x8*)&Bs[(wn * 64 + ni * 16 + lc) * 32 + lr * 8];
        #pragma unroll
        for (int mi = 0; mi < 4; ++mi)
            #pragma unroll
            for (int ni = 0; ni < 4; ++ni)
                acc[mi][ni] = __builtin_amdgcn_mfma_f32_16x16x32_bf16(
                    af[mi], bfr[ni], acc[mi][ni], 0, 0, 0);
    }

    #pragma unroll
    for (int mi = 0; mi < 4; ++mi) {
        #pragma unroll
        for (int ni = 0; ni < 4; ++ni) {
            int col = n0 + wn * 64 + ni * 16 + lc;
            float bv = bias[col];
            if (MODE == 1) {
                int sec = col >> 10, rem = col & 1023;
                int h = rem >> 6, d = rem & 63;
                int row0 = m0 + wm * 64 + mi * 16 + lr * 4;
                int b = row0 >> 11, s0 = row0 & 2047;
                long idxSD = ((long)((b << 4) + h) * 2048 + s0) * 64 + d;
                if (sec == 0) {
                    #pragma unroll
                    for (int i = 0; i < 4; ++i) {
                        float val = acc[mi][ni][i] + bv;
                        // bake attn scale 1/8 and log2(e) for exp2-domain softmax
                        qbf[idxSD + (long)i * 64] = f2bf(val * 0.1803368801111244f);
                    }
                } else if (sec == 1) {
                    #pragma unroll
                    for (int i = 0; i < 4; ++i) {
                        float val = acc[mi][ni][i] + bv;
                        kout[idxSD + (long)i * 64] = val;
                        kbf[idxSD + (long)i * 64] = f2bf(val);
                    }
                } else {
                    #pragma unroll
                    for (int i = 0; i < 4; ++i) {
                        float val = acc[mi][ni][i] + bv;
                        vout[idxSD + (long)i * 64] = val;  // fp32 V out; vT_bf made by transpose_v
                    }
                }
            } else {
                #pragma unroll
                for (int i = 0; i < 4; ++i) {
                    int row = m0 + wm * 64 + mi * 16 + lr * 4 + i;
                    outf[(long)row * N + col] = acc[mi][ni][i] + bv;
                }
            }
        }
    }
}

// ---------------- flash attention (32x32 MFMA, 2-wave blocks, BALANCED CU mapping) -----
// grid: 1024 blocks = 32 bh x 32 q-tiles of 64 rows; 128 threads (2 waves x 32 q-rows).
// Dispatch model: bid%8 -> XCD; within an XCD, slot j=bid>>3 lands on CU j%32, so one CU
// receives slots {c, c+32, c+64, c+96} (grp = j>>5 = 0..3, one each).
// ROUND-13 BUG: qt = 31-(j&31) is invariant under +32 -> all 4 blocks on a CU had the SAME
// qt -> cross-CU imbalance (qt=31 CUs: 128 step-units; qt=0 CUs: 4) -> occupancy 8.8%.
// FIX: qt(i,grp) = {i, 31-i, (i+16)&31, (15-i)&31} for grp 0..3 (i = j&31). Per-CU qt-sum
// = 62 for EVERY i; per head (head = grp) i->qt is a bijection. Every CU gets identical
// total work and a deep/shallow mix co-resident from t=0.
// Everything else identical to round 13 (verified): 64-key steps, K/V^T staged once per
// block (global_load_lds w16, dbuf, chunk XOR-swizzle both-sides), 32x32x16 MFMAs,
// pi-permuted in-register P (f2bf pack, V^T via two b64 reads), static softmax.
__global__ __launch_bounds__(128, 2) void attn_kernel(const short* __restrict__ qbf,
                                                      const short* __restrict__ kbf,
                                                      const short* __restrict__ vbfT,
                                                      short* __restrict__ obf) {
    const int bid = blockIdx.x;
    const int xcd = bid & 7, slot = bid >> 3;   // 128 slots per XCD
    const int si = slot & 31, grp = slot >> 5;  // CU index within XCD, block group
    const int base = (grp & 2) ? ((si + 16) & 31) : si;
    const int qt = (grp & 1) ? (31 - base) : base;      // balanced: per-CU qt-sum = 62
    const int bh = xcd * 4 + grp;               // 4 heads per XCD (K/V L2-resident)
    const int tid = threadIdx.x;
    const int wv = tid >> 6, l = tid & 63;      // wv in 0..1
    const int h = l >> 5;                        // lane half
    const int l8 = l & 7;
    const int q0 = qt * 64 + wv * 32;            // this wave's 32-q strip
    const int qlane = q0 + (l & 31);
    const long baseSD = (long)bh * 2048 * 64;   // q,k: [S][64]
    const long baseDS = (long)bh * 64 * 2048;   // vT:  [64][S]

    __shared__ __align__(16) short Ks[2][64 * 64];  // swizzled K tile   (8 KB x2)
    __shared__ __align__(16) short Vs[2][64 * 64];  // swizzled V^T tile (8 KB x2)

    // staging: wave wv stages rows wv*32..wv*32+31 (4 chunks of 8 rows each);
    // lane l -> row base+(l>>3), phys chunk l&7 holds logical chunk (l&7)^(l>>3).
    const int sSub = l >> 3;
    const int sChunk = (l & 7) ^ sSub;
    auto stage = [&](int kt, int nb) {
        const int k0 = kt * 64;
        const int r0 = wv * 32 + sSub;
        #pragma unroll
        for (int rr = 0; rr < 4; ++rr) {
            gload_lds16(kbf + baseSD + (long)(k0 + r0 + rr * 8) * 64 + sChunk * 8,
                        &Ks[nb][(wv * 32 + rr * 8) * 64]);
            gload_lds16(vbfT + baseDS + (long)(r0 + rr * 8) * 2048 + k0 + sChunk * 8,
                        &Vs[nb][(wv * 32 + rr * 8) * 64]);
        }
    };

    // Q fragments (B-operand, 32x32x16): lane holds col q = qlane, kdim d = dd*16 + h*8 + j
    s16x8 qf[4];
    #pragma unroll
    for (int dd = 0; dd < 4; ++dd)
        qf[dd] = *(const s16x8*)&qbf[baseSD + (long)qlane * 64 + dd * 16 + h * 8];

    float lsum = 0.f;                  // per-lane PARTIAL sum over this lane's k-subset
    f32x16 O[2] = {};                  // O^T: O[dt2][rr] = O[d = dt2*32+(rr&3)+8*(rr>>2)+4h][qlane]

    const int nkt = qt + 1;            // k-tiles covering keys 0..qt*64+63

    stage(0, 0);
    __syncthreads();                   // drains vmcnt -> buf0 ready
    int cur = 0;

    for (int kt = 0; kt < nkt; ++kt) {
        const int k0 = kt * 64;
        if (kt + 1 < nkt) stage(kt + 1, cur ^ 1);

        if (k0 <= q0 + 31) {           // strip has unmasked keys in this tile
            const short* Kb = Ks[cur];
            const short* Vb = Vs[cur];
            #pragma unroll
            for (int kk2 = 0; kk2 < 2; ++kk2) {
                // QK: S^T[32k x 32q] accumulated over d
                f32x16 z = {};
                #pragma unroll
                for (int dd = 0; dd < 4; ++dd) {
                    s16x8 kf = *(const s16x8*)&Kb[(kk2 * 32 + (l & 31)) * 64 +
                                                  (((2 * dd + h) ^ l8) * 8)];
                    z = __builtin_amdgcn_mfma_f32_32x32x16_bf16(kf, qf[dd], z, 0, 0, 0);
                }
                // causal mask: k = k0 + kk2*32 + (rr&3)+8*(rr>>2)+4h, q = qlane
                if (k0 + 63 > q0) {
                    #pragma unroll
                    for (int rr = 0; rr < 16; ++rr) {
                        int kpos = k0 + kk2 * 32 + (rr & 3) + 8 * (rr >> 2) + 4 * h;
                        if (kpos > qlane) z[rr] = -INFINITY;
                    }
                }
                // static softmax: p = exp2(s'); exp2(-inf) = 0 handles the mask
                float p[16];
                #pragma unroll
                for (int rr = 0; rr < 16; ++rr) {
                    p[rr] = __builtin_amdgcn_exp2f(z[rr]);
                    lsum += p[rr];
                }
                // PV per 16-k fragment f (k base fb = kk2*32 + f*16), pi-permuted kdim:
                //   B = pack of own p[f*8..f*8+7] (f2bf, in order);
                //   A = V^T rows, two b64 at k = fb+4h and fb+8+4h.
                #pragma unroll
                for (int f = 0; f < 2; ++f) {
                    s16x8 pf;
                    #pragma unroll
                    for (int j = 0; j < 8; ++j) pf[j] = f2bf(p[f * 8 + j]);
                    const int c0 = kk2 * 4 + f * 2;       // logical chunk of fb
                    #pragma unroll
                    for (int dt2 = 0; dt2 < 2; ++dt2) {
                        const short* vr = &Vb[(dt2 * 32 + (l & 31)) * 64];
                        s16x8 vf;
                        *(s16x4*)&vf = *(const s16x4*)&vr[(c0 ^ l8) * 8 + 4 * h];
                        *(((s16x4*)&vf) + 1) = *(const s16x4*)&vr[((c0 + 1) ^ l8) * 8 + 4 * h];
                        O[dt2] = __builtin_amdgcn_mfma_f32_32x32x16_bf16(vf, pf,
                                                                         O[dt2], 0, 0, 0);
                    }
                }
            }
        }
        __syncthreads();               // all done with buf[cur]; stage(kt+1) drained
        cur ^= 1;
    }

    // epilogue: merge lane halves' partial lsum (1 shuffle), O /= lsum; packed 8B stores
    lsum += __shfl_xor(lsum, 32);
    const int b = bh >> 4, hd = bh & 15;
    float inv = 1.0f / lsum;
    #pragma unroll
    for (int dt2 = 0; dt2 < 2; ++dt2) {
        #pragma unroll
        for (int g = 0; g < 4; ++g) {
            s16x4 o;
            #pragma unroll
            for (int i = 0; i < 4; ++i) o[i] = f2bf(O[dt2][g * 4 + i] * inv);
            const int d = dt2 * 32 + 8 * g + 4 * h;
            *(s16x4*)&obf[(long)(b * 2048 + qlane) * 1024 + hd * 64 + d] = o;
        }
    }
}

// ---------------- launch ----------------

extern "C" void kernel_launch(void* const* d_in, const int* in_sizes, int n_in,
                              void* d_out, int out_size, void* d_ws, size_t ws_size,
                              hipStream_t stream) {
    const float* x = (const float*)d_in[0];
    const float* qkv_w = (const float*)d_in[1];
    const float* qkv_b = (const float*)d_in[2];
    const float* proj_w = (const float*)d_in[3];
    const float* proj_b = (const float*)d_in[4];

    float* out = (float*)d_out;
    float* kout = out + 4194304;
    float* vout = out + 8388608;

    short* x_bf = (short*)d_ws;           // 4194304 shorts
    short* wT1 = x_bf + 4194304;          // 3145728
    short* wT2 = wT1 + 3145728;           // 1048576
    short* q_bf = wT2 + 1048576;          // 4194304
    short* k_bf = q_bf + 4194304;         // 4194304
    short* vT_bf = k_bf + 4194304;        // 4194304 ([B,H,D,S])
    short* o_bf = x_bf;                   // alias: x_bf dead after GEMM1

    convert_f32_bf16<<<2048, 256, 0, stream>>>(x, x_bf, 4194304);
    transpose_conv<<<dim3(96, 32), dim3(32, 8), 0, stream>>>(qkv_w, wT1, 1024, 3072);
    transpose_conv<<<dim3(32, 32), dim3(32, 8), 0, stream>>>(proj_w, wT2, 1024, 1024);

    gemm_bf16<1><<<dim3(24, 32), 256, 0, stream>>>(x_bf, wT1, qkv_b, 4096, 3072, 1024,
                                                   nullptr, q_bf, k_bf, kout, vout);

    transpose_v<<<dim3(64, 2, 32), dim3(32, 8), 0, stream>>>(vout, vT_bf);

    attn_kernel<<<1024, 128, 0, stream>>>(q_bf, k_bf, vT_bf, o_bf);

    gemm_bf16<2><<<dim3(8, 32), 256, 0, stream>>>(o_bf, wT2, proj_b, 4096, 1024, 1024,
                                                  out, nullptr, nullptr, nullptr, nullptr);
}

// Round 15
// 134.815 us; speedup vs baseline: 1.1238x; 1.0187x over previous
//
#include <hip/hip_runtime.h>
#include <hip/hip_bf16.h>

// Shapes (fixed): B=2, S=2048, E=1024, H=16, D=64
// d_out: out[4194304] fp32 | k[4194304] fp32 [B,H,S,D] | v[4194304] fp32 [B,H,S,D]
// ws: x_bf | wT1 | wT2 | q_bf | k_bf | vT_bf ; o_bf aliases x_bf.

typedef __attribute__((ext_vector_type(4))) float f32x4;
typedef __attribute__((ext_vector_type(16))) float f32x16;
typedef __attribute__((ext_vector_type(8))) short s16x8;
typedef __attribute__((ext_vector_type(4))) short s16x4;

__device__ __forceinline__ short f2bf(float f) {
    union { float f; unsigned u; } x{f};
    unsigned r = x.u + 0x7fff + ((x.u >> 16) & 1);
    return (short)(r >> 16);
}

__device__ __forceinline__ void gload_lds16(const void* g, void* l) {
    __builtin_amdgcn_global_load_lds(
        (const __attribute__((address_space(1))) void*)g,
        (__attribute__((address_space(3))) void*)l, 16, 0, 0);
}

// ---------------- pre-pass kernels ----------------

__global__ __launch_bounds__(256) void convert_f32_bf16(const float* __restrict__ in,
                                                        short* __restrict__ out, int n) {
    int i = (blockIdx.x * 256 + threadIdx.x) * 8;
    if (i + 7 < n) {
        f32x4 a = *(const f32x4*)&in[i];
        f32x4 b = *(const f32x4*)&in[i + 4];
        s16x8 o;
        #pragma unroll
        for (int j = 0; j < 4; ++j) o[j] = f2bf(a[j]);
        #pragma unroll
        for (int j = 0; j < 4; ++j) o[j + 4] = f2bf(b[j]);
        *(s16x8*)&out[i] = o;
    }
}

// in: [K][N] fp32 row-major -> out: [N][K] bf16 row-major
__global__ __launch_bounds__(256) void transpose_conv(const float* __restrict__ in,
                                                      short* __restrict__ out, int K, int N) {
    __shared__ float tile[32][33];
    int tx = threadIdx.x, ty = threadIdx.y;  // 32 x 8
    int n0 = blockIdx.x * 32, k0 = blockIdx.y * 32;
    #pragma unroll
    for (int r = 0; r < 4; ++r)
        tile[ty + r * 8][tx] = in[(long)(k0 + ty + r * 8) * N + n0 + tx];
    __syncthreads();
    #pragma unroll
    for (int r = 0; r < 4; ++r)
        out[(long)(n0 + ty + r * 8) * K + k0 + tx] = f2bf(tile[tx][ty + r * 8]);
}

// vout fp32 [32][2048][64] (in d_out) -> vT_bf [32][64][2048] bf16, coalesced both sides
__global__ __launch_bounds__(256) void transpose_v(const float* __restrict__ vin,
                                                   short* __restrict__ vT) {
    __shared__ float tile[32][33];
    const int bh = blockIdx.z;
    const int s0 = blockIdx.x * 32, d0 = blockIdx.y * 32;
    const int tx = threadIdx.x, ty = threadIdx.y;  // 32 x 8
    const float* src = vin + (long)bh * 2048 * 64;
    short* dst = vT + (long)bh * 64 * 2048;
    #pragma unroll
    for (int r = 0; r < 4; ++r)
        tile[ty + r * 8][tx] = src[(long)(s0 + ty + r * 8) * 64 + d0 + tx];
    __syncthreads();
    #pragma unroll
    for (int r = 0; r < 4; ++r)
        dst[(long)(d0 + ty + r * 8) * 2048 + s0 + tx] = f2bf(tile[tx][ty + r * 8]);
}

// ---------------- GEMM (m97-style: 128x128 tile, BK=32, global_load_lds) ----------------
// A: [M][K] bf16, Bt: [N][K] bf16.  MODE 1: qkv epilogue. MODE 2: plain bias epilogue.

template <int MODE>
__global__ __launch_bounds__(256) void gemm_bf16(
    const short* __restrict__ A, const short* __restrict__ Bt,
    const float* __restrict__ bias, int M, int N, int K,
    float* __restrict__ outf,
    short* __restrict__ qbf, short* __restrict__ kbf,
    float* __restrict__ kout, float* __restrict__ vout) {
    __shared__ __align__(16) short As[128 * 32];
    __shared__ __align__(16) short Bs[128 * 32];
    const int tid = threadIdx.x;
    const int l = tid & 63, w = tid >> 6;
    const int lr = l >> 4, lc = l & 15;
    const int wm = w >> 1, wn = w & 1;
    const int m0 = blockIdx.y * 128, n0 = blockIdx.x * 128;

    f32x4 acc[4][4] = {};
    const int c0 = tid, c1 = tid + 256;  // 16B chunks; chunk c -> row c>>2, seg c&3

    for (int kb = 0; kb < K; kb += 32) {
        __syncthreads();
        gload_lds16(A + (long)(m0 + (c0 >> 2)) * K + kb + (c0 & 3) * 8, As + c0 * 8);
        gload_lds16(A + (long)(m0 + (c1 >> 2)) * K + kb + (c1 & 3) * 8, As + c1 * 8);
        gload_lds16(Bt + (long)(n0 + (c0 >> 2)) * K + kb + (c0 & 3) * 8, Bs + c0 * 8);
        gload_lds16(Bt + (long)(n0 + (c1 >> 2)) * K + kb + (c1 & 3) * 8, Bs + c1 * 8);
        __syncthreads();
        s16x8 af[4], bfr[4];
        #pragma unroll
        for (int mi = 0; mi < 4; ++mi)
            af[mi] = *(const s16x8*)&As[(wm * 64 + mi * 16 + lc) * 32 + lr * 8];
        #pragma unroll
        for (int ni = 0; ni < 4; ++ni)
            bfr[ni] = *(const s16x8*)&Bs[(wn * 64 + ni * 16 + lc) * 32 + lr * 8];
        #pragma unroll
        for (int mi = 0; mi < 4; ++mi)
            #pragma unroll
            for (int ni = 0; ni < 4; ++ni)
                acc[mi][ni] = __builtin_amdgcn_mfma_f32_16x16x32_bf16(
                    af[mi], bfr[ni], acc[mi][ni], 0, 0, 0);
    }

    #pragma unroll
    for (int mi = 0; mi < 4; ++mi) {
        #pragma unroll
        for (int ni = 0; ni < 4; ++ni) {
            int col = n0 + wn * 64 + ni * 16 + lc;
            float bv = bias[col];
            if (MODE == 1) {
                int sec = col >> 10, rem = col & 1023;
                int h = rem >> 6, d = rem & 63;
                int row0 = m0 + wm * 64 + mi * 16 + lr * 4;
                int b = row0 >> 11, s0 = row0 & 2047;
                long idxSD = ((long)((b << 4) + h) * 2048 + s0) * 64 + d;
                if (sec == 0) {
                    #pragma unroll
                    for (int i = 0; i < 4; ++i) {
                        float val = acc[mi][ni][i] + bv;
                        // bake attn scale 1/8 and log2(e) for exp2-domain softmax
                        qbf[idxSD + (long)i * 64] = f2bf(val * 0.1803368801111244f);
                    }
                } else if (sec == 1) {
                    #pragma unroll
                    for (int i = 0; i < 4; ++i) {
                        float val = acc[mi][ni][i] + bv;
                        kout[idxSD + (long)i * 64] = val;
                        kbf[idxSD + (long)i * 64] = f2bf(val);
                    }
                } else {
                    #pragma unroll
                    for (int i = 0; i < 4; ++i) {
                        float val = acc[mi][ni][i] + bv;
                        vout[idxSD + (long)i * 64] = val;  // fp32 V out; vT_bf made by transpose_v
                    }
                }
            } else {
                #pragma unroll
                for (int i = 0; i < 4; ++i) {
                    int row = m0 + wm * 64 + mi * 16 + lr * 4 + i;
                    outf[(long)row * N + col] = acc[mi][ni][i] + bv;
                }
            }
        }
    }
}

// ---------------- flash attention (32x32 MFMA, in-reg P, COUNTED-VMCNT pipeline) -------
// grid: 512 blocks = 32 bh x 16 q-tiles of 128 rows; 256 threads (4 waves x 32 q-rows).
// Round-12 base (best passing variant). THIS ROUND: replace __syncthreads() (which drains
// vmcnt to 0 -> each step eats a full L2 round-trip of the prefetch) with raw s_barrier +
// COUNTED s_waitcnt vmcnt(4) (T3/T4): stage(t+1)'s 4 global_load_lds stay in flight across
// BOTH barriers and all of step t's compute, landing just before step t+1 needs them.
//   per-iter: [issue stage(t+1)] -> vmcnt(4) (=stage(t) done; 4 newer still flying)
//             -> s_barrier -> compute(buf[t]) -> ""::memory pin -> s_barrier.
// Last iter waits vmcnt(0). "memory"-clobber asm prevents hoisting LDS reads above the
// wait or sinking them past the end barrier (dbuf overwrite hazard).
// T5: s_setprio(1) around MFMA clusters (2 independent blocks/CU give role diversity).
// Rest identical to round 12: chunk XOR-swizzle both-sides staging, 32x32x16 MFMAs,
// pi-permuted in-register P (f2bf pack, V^T two b64 reads), static softmax (p = exp2(s'),
// causal rows contain the diagonal -> row max p in [1, 2^~26]).
__global__ __launch_bounds__(256, 2) void attn_kernel(const short* __restrict__ qbf,
                                                      const short* __restrict__ kbf,
                                                      const short* __restrict__ vbfT,
                                                      short* __restrict__ obf) {
    const int bid = blockIdx.x;
    const int xcd = bid & 7, r = bid >> 3;      // 64 slots per XCD
    const int head_local = r & 3, q16 = r >> 2; // q16 in 0..15
    const int qt = (q16 < 8) ? (q16 + 8) : (15 - q16);  // slot r and r+32 sum to 34 steps
    const int bh = xcd * 4 + head_local;
    const int tid = threadIdx.x;
    const int wv = tid >> 6, l = tid & 63;      // wv in 0..3
    const int h = l >> 5;                        // lane half
    const int l8 = l & 7;
    const int q0 = qt * 128 + wv * 32;           // this wave's 32-q strip
    const int qlane = q0 + (l & 31);
    const long baseSD = (long)bh * 2048 * 64;   // q,k: [S][64]
    const long baseDS = (long)bh * 64 * 2048;   // vT:  [64][S]

    __shared__ __align__(16) short Ks[2][64 * 64];  // swizzled K tile   (8 KB x2)
    __shared__ __align__(16) short Vs[2][64 * 64];  // swizzled V^T tile (8 KB x2)

    // staging: wave wv stages rows wv*16..wv*16+15; lane l -> row base+(l>>3),
    // phys chunk l&7 holds logical chunk (l&7)^(l>>3)  (row&7 == l>>3). 4 gload_lds/wave.
    const int sSub = l >> 3;
    const int sChunk = (l & 7) ^ sSub;
    auto stage = [&](int kt, int nb) {
        const int k0 = kt * 64;
        const int r0 = wv * 16 + sSub;
        gload_lds16(kbf + baseSD + (long)(k0 + r0) * 64 + sChunk * 8,
                    &Ks[nb][(wv * 16) * 64]);
        gload_lds16(kbf + baseSD + (long)(k0 + r0 + 8) * 64 + sChunk * 8,
                    &Ks[nb][(wv * 16 + 8) * 64]);
        gload_lds16(vbfT + baseDS + (long)r0 * 2048 + k0 + sChunk * 8,
                    &Vs[nb][(wv * 16) * 64]);
        gload_lds16(vbfT + baseDS + (long)(r0 + 8) * 2048 + k0 + sChunk * 8,
                    &Vs[nb][(wv * 16 + 8) * 64]);
    };

    // Q fragments (B-operand, 32x32x16): lane holds col q = qlane, kdim d = dd*16 + h*8 + j
    s16x8 qf[4];
    #pragma unroll
    for (int dd = 0; dd < 4; ++dd)
        qf[dd] = *(const s16x8*)&qbf[baseSD + (long)qlane * 64 + dd * 16 + h * 8];

    float lsum = 0.f;                  // per-lane PARTIAL sum over this lane's k-subset
    f32x16 O[2] = {};                  // O^T: O[dt2][rr] = O[d = dt2*32+(rr&3)+8*(rr>>2)+4h][qlane]

    const int nkt = 2 * qt + 2;        // k-tiles covering rows 0..qt*128+127

    stage(0, 0);                       // 4 loads in flight; iter 0's vmcnt(4) covers them
    int cur = 0;

    for (int kt = 0; kt < nkt; ++kt) {
        const int k0 = kt * 64;
        if (kt + 1 < nkt) {
            stage(kt + 1, cur ^ 1);                          // 4 more loads -> 8 in flight
            asm volatile("s_waitcnt vmcnt(4)" ::: "memory"); // stage(kt) complete
        } else {
            asm volatile("s_waitcnt vmcnt(0)" ::: "memory");
        }
        __builtin_amdgcn_s_barrier();   // all waves' stage(kt) landed; NO full drain

        if (k0 <= q0 + 31) {           // strip has unmasked keys in this tile
            const short* Kb = Ks[cur];
            const short* Vb = Vs[cur];
            #pragma unroll
            for (int kk2 = 0; kk2 < 2; ++kk2) {
                // QK: S^T[32k x 32q] accumulated over d
                f32x16 z = {};
                __builtin_amdgcn_s_setprio(1);
                #pragma unroll
                for (int dd = 0; dd < 4; ++dd) {
                    s16x8 kf = *(const s16x8*)&Kb[(kk2 * 32 + (l & 31)) * 64 +
                                                  (((2 * dd + h) ^ l8) * 8)];
                    z = __builtin_amdgcn_mfma_f32_32x32x16_bf16(kf, qf[dd], z, 0, 0, 0);
                }
                __builtin_amdgcn_s_setprio(0);
                // causal mask: k = k0 + kk2*32 + (rr&3)+8*(rr>>2)+4h, q = qlane
                if (k0 + 63 > q0) {
                    #pragma unroll
                    for (int rr = 0; rr < 16; ++rr) {
                        int kpos = k0 + kk2 * 32 + (rr & 3) + 8 * (rr >> 2) + 4 * h;
                        if (kpos > qlane) z[rr] = -INFINITY;
                    }
                }
                // static softmax: p = exp2(s'); exp2(-inf) = 0 handles the mask
                float p[16];
                #pragma unroll
                for (int rr = 0; rr < 16; ++rr) {
                    p[rr] = __builtin_amdgcn_exp2f(z[rr]);
                    lsum += p[rr];
                }
                // PV per 16-k fragment f (k base fb = kk2*32 + f*16), pi-permuted kdim:
                //   B = pack of own p[f*8..f*8+7] (f2bf, in order);
                //   A = V^T rows, two b64 at k = fb+4h and fb+8+4h.
                #pragma unroll
                for (int f = 0; f < 2; ++f) {
                    s16x8 pf;
                    #pragma unroll
                    for (int j = 0; j < 8; ++j) pf[j] = f2bf(p[f * 8 + j]);
                    const int c0 = kk2 * 4 + f * 2;       // logical chunk of fb
                    __builtin_amdgcn_s_setprio(1);
                    #pragma unroll
                    for (int dt2 = 0; dt2 < 2; ++dt2) {
                        const short* vr = &Vb[(dt2 * 32 + (l & 31)) * 64];
                        s16x8 vf;
                        *(s16x4*)&vf = *(const s16x4*)&vr[(c0 ^ l8) * 8 + 4 * h];
                        *(((s16x4*)&vf) + 1) = *(const s16x4*)&vr[((c0 + 1) ^ l8) * 8 + 4 * h];
                        O[dt2] = __builtin_amdgcn_mfma_f32_32x32x16_bf16(vf, pf,
                                                                         O[dt2], 0, 0, 0);
                    }
                    __builtin_amdgcn_s_setprio(0);
                }
            }
        }
        asm volatile("" ::: "memory");  // pin LDS reads before the overwrite-protect barrier
        __builtin_amdgcn_s_barrier();   // all waves done reading buf[cur]
        cur ^= 1;
    }

    // epilogue: merge lane halves' partial lsum (1 shuffle), O /= lsum; packed 8B stores
    lsum += __shfl_xor(lsum, 32);
    const int b = bh >> 4, hd = bh & 15;
    float inv = 1.0f / lsum;
    #pragma unroll
    for (int dt2 = 0; dt2 < 2; ++dt2) {
        #pragma unroll
        for (int g = 0; g < 4; ++g) {
            s16x4 o;
            #pragma unroll
            for (int i = 0; i < 4; ++i) o[i] = f2bf(O[dt2][g * 4 + i] * inv);
            const int d = dt2 * 32 + 8 * g + 4 * h;
            *(s16x4*)&obf[(long)(b * 2048 + qlane) * 1024 + hd * 64 + d] = o;
        }
    }
}

// ---------------- launch ----------------

extern "C" void kernel_launch(void* const* d_in, const int* in_sizes, int n_in,
                              void* d_out, int out_size, void* d_ws, size_t ws_size,
                              hipStream_t stream) {
    const float* x = (const float*)d_in[0];
    const float* qkv_w = (const float*)d_in[1];
    const float* qkv_b = (const float*)d_in[2];
    const float* proj_w = (const float*)d_in[3];
    const float* proj_b = (const float*)d_in[4];

    float* out = (float*)d_out;
    float* kout = out + 4194304;
    float* vout = out + 8388608;

    short* x_bf = (short*)d_ws;           // 4194304 shorts
    short* wT1 = x_bf + 4194304;          // 3145728
    short* wT2 = wT1 + 3145728;           // 1048576
    short* q_bf = wT2 + 1048576;          // 4194304
    short* k_bf = q_bf + 4194304;         // 4194304
    short* vT_bf = k_bf + 4194304;        // 4194304 ([B,H,D,S])
    short* o_bf = x_bf;                   // alias: x_bf dead after GEMM1

    convert_f32_bf16<<<2048, 256, 0, stream>>>(x, x_bf, 4194304);
    transpose_conv<<<dim3(96, 32), dim3(32, 8), 0, stream>>>(qkv_w, wT1, 1024, 3072);
    transpose_conv<<<dim3(32, 32), dim3(32, 8), 0, stream>>>(proj_w, wT2, 1024, 1024);

    gemm_bf16<1><<<dim3(24, 32), 256, 0, stream>>>(x_bf, wT1, qkv_b, 4096, 3072, 1024,
                                                   nullptr, q_bf, k_bf, kout, vout);

    transpose_v<<<dim3(64, 2, 32), dim3(32, 8), 0, stream>>>(vout, vT_bf);

    attn_kernel<<<512, 256, 0, stream>>>(q_bf, k_bf, vT_bf, o_bf);

    gemm_bf16<2><<<dim3(8, 32), 256, 0, stream>>>(o_bf, wT2, proj_b, 4096, 1024, 1024,
                                                  out, nullptr, nullptr, nullptr, nullptr);
}

// Round 16
// 121.316 us; speedup vs baseline: 1.2488x; 1.1113x over previous
//
#include <hip/hip_runtime.h>
#include <hip/hip_bf16.h>

// Shapes (fixed): B=2, S=2048, E=1024, H=16, D=64
// d_out: out[4194304] fp32 | k[4194304] fp32 [B,H,S,D] | v[4194304] fp32 [B,H,S,D]
// ws: x_bf | wT1 | wT2 | q_bf | k_bf | vT_bf ; o_bf aliases x_bf.

typedef __attribute__((ext_vector_type(4))) float f32x4;
typedef __attribute__((ext_vector_type(16))) float f32x16;
typedef __attribute__((ext_vector_type(8))) short s16x8;
typedef __attribute__((ext_vector_type(4))) short s16x4;

__device__ __forceinline__ short f2bf(float f) {
    union { float f; unsigned u; } x{f};
    unsigned r = x.u + 0x7fff + ((x.u >> 16) & 1);
    return (short)(r >> 16);
}

__device__ __forceinline__ void gload_lds16(const void* g, void* l) {
    __builtin_amdgcn_global_load_lds(
        (const __attribute__((address_space(1))) void*)g,
        (__attribute__((address_space(3))) void*)l, 16, 0, 0);
}

// ---------------- fused pre-pass (1 launch instead of 3) ----------------
// blocks [0,2048):        x fp32 -> x_bf (8 elems/thread)
// blocks [2048,5120):     qkv_w [1024][3072] -> wT1 [3072][1024] bf16
// blocks [5120,6144):     proj_w [1024][1024] -> wT2 [1024][1024] bf16
__global__ __launch_bounds__(256) void fused_prepass(const float* __restrict__ x,
                                                     short* __restrict__ x_bf,
                                                     const float* __restrict__ qkv_w,
                                                     short* __restrict__ wT1,
                                                     const float* __restrict__ proj_w,
                                                     short* __restrict__ wT2) {
    __shared__ float tile[32][33];
    const int bid = blockIdx.x, tid = threadIdx.x;
    if (bid < 2048) {
        int i = (bid * 256 + tid) * 8;
        f32x4 a = *(const f32x4*)&x[i];
        f32x4 b = *(const f32x4*)&x[i + 4];
        s16x8 o;
        #pragma unroll
        for (int j = 0; j < 4; ++j) o[j] = f2bf(a[j]);
        #pragma unroll
        for (int j = 0; j < 4; ++j) o[j + 4] = f2bf(b[j]);
        *(s16x8*)&x_bf[i] = o;
        return;
    }
    const float* in;
    short* out;
    int K = 1024, N, n0, k0;
    if (bid < 5120) {
        int blk = bid - 2048;
        in = qkv_w; out = wT1; N = 3072;
        n0 = (blk % 96) * 32; k0 = (blk / 96) * 32;
    } else {
        int blk = bid - 5120;
        in = proj_w; out = wT2; N = 1024;
        n0 = (blk & 31) * 32; k0 = (blk >> 5) * 32;
    }
    const int tx = tid & 31, ty = tid >> 5;  // 32 x 8
    #pragma unroll
    for (int r = 0; r < 4; ++r)
        tile[ty + r * 8][tx] = in[(long)(k0 + ty + r * 8) * N + n0 + tx];
    __syncthreads();
    #pragma unroll
    for (int r = 0; r < 4; ++r)
        out[(long)(n0 + ty + r * 8) * K + k0 + tx] = f2bf(tile[tx][ty + r * 8]);
}

// ---------------- GEMM (m97-style: 128x128 tile, BK=32, global_load_lds) ----------------
// A: [M][K] bf16, Bt: [N][K] bf16.  MODE 1: qkv epilogue (q/k/v scatter + vT). MODE 2: bias.

template <int MODE>
__global__ __launch_bounds__(256) void gemm_bf16(
    const short* __restrict__ A, const short* __restrict__ Bt,
    const float* __restrict__ bias, int M, int N, int K,
    float* __restrict__ outf,
    short* __restrict__ qbf, short* __restrict__ kbf, short* __restrict__ vbfT,
    float* __restrict__ kout, float* __restrict__ vout) {
    __shared__ __align__(16) short As[128 * 32];
    __shared__ __align__(16) short Bs[128 * 32];
    const int tid = threadIdx.x;
    const int l = tid & 63, w = tid >> 6;
    const int lr = l >> 4, lc = l & 15;
    const int wm = w >> 1, wn = w & 1;
    const int m0 = blockIdx.y * 128, n0 = blockIdx.x * 128;

    f32x4 acc[4][4] = {};
    const int c0 = tid, c1 = tid + 256;  // 16B chunks; chunk c -> row c>>2, seg c&3

    for (int kb = 0; kb < K; kb += 32) {
        __syncthreads();
        gload_lds16(A + (long)(m0 + (c0 >> 2)) * K + kb + (c0 & 3) * 8, As + c0 * 8);
        gload_lds16(A + (long)(m0 + (c1 >> 2)) * K + kb + (c1 & 3) * 8, As + c1 * 8);
        gload_lds16(Bt + (long)(n0 + (c0 >> 2)) * K + kb + (c0 & 3) * 8, Bs + c0 * 8);
        gload_lds16(Bt + (long)(n0 + (c1 >> 2)) * K + kb + (c1 & 3) * 8, Bs + c1 * 8);
        __syncthreads();
        s16x8 af[4], bfr[4];
        #pragma unroll
        for (int mi = 0; mi < 4; ++mi)
            af[mi] = *(const s16x8*)&As[(wm * 64 + mi * 16 + lc) * 32 + lr * 8];
        #pragma unroll
        for (int ni = 0; ni < 4; ++ni)
            bfr[ni] = *(const s16x8*)&Bs[(wn * 64 + ni * 16 + lc) * 32 + lr * 8];
        #pragma unroll
        for (int mi = 0; mi < 4; ++mi)
            #pragma unroll
            for (int ni = 0; ni < 4; ++ni)
                acc[mi][ni] = __builtin_amdgcn_mfma_f32_16x16x32_bf16(
                    af[mi], bfr[ni], acc[mi][ni], 0, 0, 0);
    }

    #pragma unroll
    for (int mi = 0; mi < 4; ++mi) {
        #pragma unroll
        for (int ni = 0; ni < 4; ++ni) {
            int col = n0 + wn * 64 + ni * 16 + lc;
            float bv = bias[col];
            if (MODE == 1) {
                int sec = col >> 10, rem = col & 1023;
                int h = rem >> 6, d = rem & 63;
                int row0 = m0 + wm * 64 + mi * 16 + lr * 4;
                int b = row0 >> 11, s0 = row0 & 2047;
                long idxSD = ((long)((b << 4) + h) * 2048 + s0) * 64 + d;
                if (sec == 0) {
                    #pragma unroll
                    for (int i = 0; i < 4; ++i) {
                        float val = acc[mi][ni][i] + bv;
                        // bake attn scale 1/8 and log2(e) for exp2-domain softmax
                        qbf[idxSD + (long)i * 64] = f2bf(val * 0.1803368801111244f);
                    }
                } else if (sec == 1) {
                    #pragma unroll
                    for (int i = 0; i < 4; ++i) {
                        float val = acc[mi][ni][i] + bv;
                        kout[idxSD + (long)i * 64] = val;
                        kbf[idxSD + (long)i * 64] = f2bf(val);
                    }
                } else {
                    s16x4 pk;
                    #pragma unroll
                    for (int i = 0; i < 4; ++i) {
                        float val = acc[mi][ni][i] + bv;
                        vout[idxSD + (long)i * 64] = val;
                        pk[i] = f2bf(val);
                    }
                    // transposed bf16 copy [B,H,D,S]: 8B packed store (round-8 style;
                    // measured cheaper in-epilogue than a separate transpose kernel)
                    *(s16x4*)&vbfT[((long)((b << 4) + h) * 64 + d) * 2048 + s0] = pk;
                }
            } else {
                #pragma unroll
                for (int i = 0; i < 4; ++i) {
                    int row = m0 + wm * 64 + mi * 16 + lr * 4 + i;
                    outf[(long)row * N + col] = acc[mi][ni][i] + bv;
                }
            }
        }
    }
}

// ---------------- flash attention (round-12 structure + VALU-chain cut) ----------------
// grid: 512 blocks = 32 bh x 16 q-tiles of 128 rows; 256 threads (4 waves x 32 q-rows).
// Per 64-key step: block stages K [64k][64d] + V^T [64d][64k] once (global_load_lds w16,
// double-buffered, chunk XOR-swizzle both-sides). 32x32x16 MFMAs; C-layout col q = lane&31,
// row = (r&3)+8*(r>>2)+4*(lane>>5). P in registers via kdim permutation pi (verified r12).
// THIS ROUND (VALU cut): P-pack via __float22bfloat162_rn (v_cvt_pk_bf16_f32 through the
// compiler, 16 ops vs 96 bit-twiddle ops) and lsum split into 4 independent accumulators
// (dependent-add chain 32 -> 8 per step).
// STATIC softmax: p = exp2(s'), no max-tracking (causal rows contain the diagonal ->
// row max p in [1, 2^~26], inside f32/bf16 range).
__global__ __launch_bounds__(256, 2) void attn_kernel(const short* __restrict__ qbf,
                                                      const short* __restrict__ kbf,
                                                      const short* __restrict__ vbfT,
                                                      short* __restrict__ obf) {
    const int bid = blockIdx.x;
    const int xcd = bid & 7, r = bid >> 3;      // 64 slots per XCD
    const int head_local = r & 3, q16 = r >> 2; // q16 in 0..15
    const int qt = (q16 < 8) ? (q16 + 8) : (15 - q16);  // slot r and r+32 sum to 34 steps
    const int bh = xcd * 4 + head_local;
    const int tid = threadIdx.x;
    const int wv = tid >> 6, l = tid & 63;      // wv in 0..3
    const int h = l >> 5;                        // lane half
    const int l8 = l & 7;
    const int q0 = qt * 128 + wv * 32;           // this wave's 32-q strip
    const int qlane = q0 + (l & 31);
    const long baseSD = (long)bh * 2048 * 64;   // q,k: [S][64]
    const long baseDS = (long)bh * 64 * 2048;   // vT:  [64][S]

    __shared__ __align__(16) short Ks[2][64 * 64];  // swizzled K tile   (8 KB x2)
    __shared__ __align__(16) short Vs[2][64 * 64];  // swizzled V^T tile (8 KB x2)

    // staging: wave wv stages rows wv*16..wv*16+15; lane l -> row base+(l>>3),
    // phys chunk l&7 holds logical chunk (l&7)^(l>>3)  (row&7 == l>>3).
    const int sSub = l >> 3;
    const int sChunk = (l & 7) ^ sSub;
    auto stage = [&](int kt, int nb) {
        const int k0 = kt * 64;
        const int r0 = wv * 16 + sSub;
        gload_lds16(kbf + baseSD + (long)(k0 + r0) * 64 + sChunk * 8,
                    &Ks[nb][(wv * 16) * 64]);
        gload_lds16(kbf + baseSD + (long)(k0 + r0 + 8) * 64 + sChunk * 8,
                    &Ks[nb][(wv * 16 + 8) * 64]);
        gload_lds16(vbfT + baseDS + (long)r0 * 2048 + k0 + sChunk * 8,
                    &Vs[nb][(wv * 16) * 64]);
        gload_lds16(vbfT + baseDS + (long)(r0 + 8) * 2048 + k0 + sChunk * 8,
                    &Vs[nb][(wv * 16 + 8) * 64]);
    };

    // Q fragments (B-operand, 32x32x16): lane holds col q = qlane, kdim d = dd*16 + h*8 + j
    s16x8 qf[4];
    #pragma unroll
    for (int dd = 0; dd < 4; ++dd)
        qf[dd] = *(const s16x8*)&qbf[baseSD + (long)qlane * 64 + dd * 16 + h * 8];

    f32x4 lacc = {};                   // 4 independent partial-sum accumulators
    f32x16 O[2] = {};                  // O^T: O[dt2][rr] = O[d = dt2*32+(rr&3)+8*(rr>>2)+4h][qlane]

    const int nkt = 2 * qt + 2;        // k-tiles covering rows 0..qt*128+127

    stage(0, 0);
    __syncthreads();                   // drains vmcnt -> buf0 ready
    int cur = 0;

    for (int kt = 0; kt < nkt; ++kt) {
        const int k0 = kt * 64;
        if (kt + 1 < nkt) stage(kt + 1, cur ^ 1);

        if (k0 <= q0 + 31) {           // strip has unmasked keys in this tile
            const short* Kb = Ks[cur];
            const short* Vb = Vs[cur];
            #pragma unroll
            for (int kk2 = 0; kk2 < 2; ++kk2) {
                // QK: S^T[32k x 32q] accumulated over d
                f32x16 z = {};
                #pragma unroll
                for (int dd = 0; dd < 4; ++dd) {
                    s16x8 kf = *(const s16x8*)&Kb[(kk2 * 32 + (l & 31)) * 64 +
                                                  (((2 * dd + h) ^ l8) * 8)];
                    z = __builtin_amdgcn_mfma_f32_32x32x16_bf16(kf, qf[dd], z, 0, 0, 0);
                }
                // causal mask: k = k0 + kk2*32 + (rr&3)+8*(rr>>2)+4h, q = qlane
                if (k0 + 63 > q0) {
                    #pragma unroll
                    for (int rr = 0; rr < 16; ++rr) {
                        int kpos = k0 + kk2 * 32 + (rr & 3) + 8 * (rr >> 2) + 4 * h;
                        if (kpos > qlane) z[rr] = -INFINITY;
                    }
                }
                // static softmax: p = exp2(s'); exp2(-inf) = 0 handles the mask
                float p[16];
                #pragma unroll
                for (int rr = 0; rr < 16; ++rr) {
                    p[rr] = __builtin_amdgcn_exp2f(z[rr]);
                    lacc[rr & 3] += p[rr];
                }
                // PV per 16-k fragment f (k base fb = kk2*32 + f*16), pi-permuted kdim:
                //   B = packed own p[f*8..f*8+7] via v_cvt_pk_bf16_f32 (builtin, RNE);
                //   A = V^T rows, two b64 at k = fb+4h and fb+8+4h.
                #pragma unroll
                for (int f = 0; f < 2; ++f) {
                    union { __hip_bfloat162 b2[4]; s16x8 v; } pk;
                    #pragma unroll
                    for (int j = 0; j < 4; ++j)
                        pk.b2[j] = __float22bfloat162_rn(
                            make_float2(p[f * 8 + 2 * j], p[f * 8 + 2 * j + 1]));
                    const int c0 = kk2 * 4 + f * 2;       // logical chunk of fb
                    #pragma unroll
                    for (int dt2 = 0; dt2 < 2; ++dt2) {
                        const short* vr = &Vb[(dt2 * 32 + (l & 31)) * 64];
                        s16x8 vf;
                        *(s16x4*)&vf = *(const s16x4*)&vr[(c0 ^ l8) * 8 + 4 * h];
                        *(((s16x4*)&vf) + 1) = *(const s16x4*)&vr[((c0 + 1) ^ l8) * 8 + 4 * h];
                        O[dt2] = __builtin_amdgcn_mfma_f32_32x32x16_bf16(vf, pk.v,
                                                                         O[dt2], 0, 0, 0);
                    }
                }
            }
        }
        __syncthreads();               // all done with buf[cur]; stage(kt+1) drained
        cur ^= 1;
    }

    // epilogue: combine 4 partials, merge lane halves (1 shuffle), O /= lsum; 8B stores
    float lsum = (lacc[0] + lacc[1]) + (lacc[2] + lacc[3]);
    lsum += __shfl_xor(lsum, 32);
    const int b = bh >> 4, hd = bh & 15;
    float inv = 1.0f / lsum;
    #pragma unroll
    for (int dt2 = 0; dt2 < 2; ++dt2) {
        #pragma unroll
        for (int g = 0; g < 4; ++g) {
            s16x4 o;
            #pragma unroll
            for (int i = 0; i < 4; ++i) o[i] = f2bf(O[dt2][g * 4 + i] * inv);
            const int d = dt2 * 32 + 8 * g + 4 * h;
            *(s16x4*)&obf[(long)(b * 2048 + qlane) * 1024 + hd * 64 + d] = o;
        }
    }
}

// ---------------- launch ----------------

extern "C" void kernel_launch(void* const* d_in, const int* in_sizes, int n_in,
                              void* d_out, int out_size, void* d_ws, size_t ws_size,
                              hipStream_t stream) {
    const float* x = (const float*)d_in[0];
    const float* qkv_w = (const float*)d_in[1];
    const float* qkv_b = (const float*)d_in[2];
    const float* proj_w = (const float*)d_in[3];
    const float* proj_b = (const float*)d_in[4];

    float* out = (float*)d_out;
    float* kout = out + 4194304;
    float* vout = out + 8388608;

    short* x_bf = (short*)d_ws;           // 4194304 shorts
    short* wT1 = x_bf + 4194304;          // 3145728
    short* wT2 = wT1 + 3145728;           // 1048576
    short* q_bf = wT2 + 1048576;          // 4194304
    short* k_bf = q_bf + 4194304;         // 4194304
    short* vT_bf = k_bf + 4194304;        // 4194304 ([B,H,D,S])
    short* o_bf = x_bf;                   // alias: x_bf dead after GEMM1

    fused_prepass<<<6144, 256, 0, stream>>>(x, x_bf, qkv_w, wT1, proj_w, wT2);

    gemm_bf16<1><<<dim3(24, 32), 256, 0, stream>>>(x_bf, wT1, qkv_b, 4096, 3072, 1024,
                                                   nullptr, q_bf, k_bf, vT_bf, kout, vout);

    attn_kernel<<<512, 256, 0, stream>>>(q_bf, k_bf, vT_bf, o_bf);

    gemm_bf16<2><<<dim3(8, 32), 256, 0, stream>>>(o_bf, wT2, proj_b, 4096, 1024, 1024,
                                                  out, nullptr, nullptr, nullptr, nullptr, nullptr);
}

// Round 17
// 109.700 us; speedup vs baseline: 1.3811x; 1.1059x over previous
//
#include <hip/hip_runtime.h>
#include <hip/hip_bf16.h>

// Shapes (fixed): B=2, S=2048, E=1024, H=16, D=64
// d_out: out[4194304] fp32 | k[4194304] fp32 [B,H,S,D] | v[4194304] fp32 [B,H,S,D]
// ws: x_bf | wT1 | wT2 | q_bf | k_bf | vT_bf ; o_bf aliases x_bf.

typedef __attribute__((ext_vector_type(4))) float f32x4;
typedef __attribute__((ext_vector_type(16))) float f32x16;
typedef __attribute__((ext_vector_type(8))) short s16x8;
typedef __attribute__((ext_vector_type(4))) short s16x4;

__device__ __forceinline__ short f2bf(float f) {
    union { float f; unsigned u; } x{f};
    unsigned r = x.u + 0x7fff + ((x.u >> 16) & 1);
    return (short)(r >> 16);
}

__device__ __forceinline__ void gload_lds16(const void* g, void* l) {
    __builtin_amdgcn_global_load_lds(
        (const __attribute__((address_space(1))) void*)g,
        (__attribute__((address_space(3))) void*)l, 16, 0, 0);
}

// ---------------- fused pre-pass (1 launch) ----------------
// blocks [0,2048):        x fp32 -> x_bf (8 elems/thread)
// blocks [2048,5120):     qkv_w [1024][3072] -> wT1 [3072][1024] bf16
// blocks [5120,6144):     proj_w [1024][1024] -> wT2 [1024][1024] bf16
__global__ __launch_bounds__(256) void fused_prepass(const float* __restrict__ x,
                                                     short* __restrict__ x_bf,
                                                     const float* __restrict__ qkv_w,
                                                     short* __restrict__ wT1,
                                                     const float* __restrict__ proj_w,
                                                     short* __restrict__ wT2) {
    __shared__ float tile[32][33];
    const int bid = blockIdx.x, tid = threadIdx.x;
    if (bid < 2048) {
        int i = (bid * 256 + tid) * 8;
        f32x4 a = *(const f32x4*)&x[i];
        f32x4 b = *(const f32x4*)&x[i + 4];
        s16x8 o;
        #pragma unroll
        for (int j = 0; j < 4; ++j) o[j] = f2bf(a[j]);
        #pragma unroll
        for (int j = 0; j < 4; ++j) o[j + 4] = f2bf(b[j]);
        *(s16x8*)&x_bf[i] = o;
        return;
    }
    const float* in;
    short* out;
    int K = 1024, N, n0, k0;
    if (bid < 5120) {
        int blk = bid - 2048;
        in = qkv_w; out = wT1; N = 3072;
        n0 = (blk % 96) * 32; k0 = (blk / 96) * 32;
    } else {
        int blk = bid - 5120;
        in = proj_w; out = wT2; N = 1024;
        n0 = (blk & 31) * 32; k0 = (blk >> 5) * 32;
    }
    const int tx = tid & 31, ty = tid >> 5;  // 32 x 8
    #pragma unroll
    for (int r = 0; r < 4; ++r)
        tile[ty + r * 8][tx] = in[(long)(k0 + ty + r * 8) * N + n0 + tx];
    __syncthreads();
    #pragma unroll
    for (int r = 0; r < 4; ++r)
        out[(long)(n0 + ty + r * 8) * K + k0 + tx] = f2bf(tile[tx][ty + r * 8]);
}

// ---------------- GEMM (128x128 tile, BK=64, XOR-swizzled LDS, XCD patch swizzle) -------
// A: [M][K] bf16, Bt: [N][K] bf16.  MODE 1: qkv epilogue (q/k/v scatter + vT). MODE 2: bias.
// BK=64 halves the per-K-step barrier count vs BK=32 (the vmcnt(0)+barrier drain was the
// dominant stall: MfmaUtil 20%). Row stride 128B would be a 16-way bank conflict (T2), so
// chunk XOR-swizzle both-sides: logical k-seg s of row r stored at phys seg s^(r&7);
// stage pre-swizzles the GLOBAL source (global_load_lds dest must stay linear, rule #21),
// fragment reads XOR on the fly -> 2-way (free). Same algebra as the attn staging (proven).
// XCD patch swizzle (1D grid): each XCD owns a contiguous bx-by patch so A/B panels stay
// in its private L2 (MODE1: 12x8 patch -> A 2MB + B 3MB; MODE2: 4x8).
template <int MODE>
__global__ __launch_bounds__(256) void gemm_bf16(
    const short* __restrict__ A, const short* __restrict__ Bt,
    const float* __restrict__ bias, int M, int N, int K,
    float* __restrict__ outf,
    short* __restrict__ qbf, short* __restrict__ kbf, short* __restrict__ vbfT,
    float* __restrict__ kout, float* __restrict__ vout) {
    __shared__ __align__(16) short As[128 * 64];
    __shared__ __align__(16) short Bs[128 * 64];
    const int tid = threadIdx.x;
    const int l = tid & 63, w = tid >> 6;
    const int lr = l >> 4, lc = l & 15;
    const int wm = w >> 1, wn = w & 1;
    // XCD patch swizzle (bijective)
    const int bid = blockIdx.x;
    const int xcd = bid & 7, s = bid >> 3;
    int bx, by;
    if (MODE == 1) { bx = (xcd & 1) * 12 + s % 12; by = (xcd >> 1) * 8 + s / 12; }
    else           { bx = (xcd & 1) * 4 + (s & 3); by = (xcd >> 1) * 8 + (s >> 2); }
    const int m0 = by * 128, n0 = bx * 128;

    f32x4 acc[4][4] = {};

    for (int kb = 0; kb < K; kb += 64) {
        __syncthreads();
        // stage: 1024 chunks of 16B per tile; thread handles chunks tid+256*j.
        // chunk c -> row c>>3, phys seg c&7 holds logical seg (c&7)^(row&7).
        #pragma unroll
        for (int j = 0; j < 4; ++j) {
            const int c = tid + 256 * j;
            const int row = c >> 3;
            const int lseg = (c & 7) ^ (row & 7);
            gload_lds16(A + (long)(m0 + row) * K + kb + lseg * 8, As + c * 8);
            gload_lds16(Bt + (long)(n0 + row) * K + kb + lseg * 8, Bs + c * 8);
        }
        __syncthreads();
        #pragma unroll
        for (int kh = 0; kh < 2; ++kh) {
            s16x8 af[4], bfr[4];
            #pragma unroll
            for (int mi = 0; mi < 4; ++mi) {
                const int row = wm * 64 + mi * 16 + lc;
                af[mi] = *(const s16x8*)&As[row * 64 + (((kh * 4 + lr) ^ (lc & 7)) * 8)];
            }
            #pragma unroll
            for (int ni = 0; ni < 4; ++ni) {
                const int row = wn * 64 + ni * 16 + lc;
                bfr[ni] = *(const s16x8*)&Bs[row * 64 + (((kh * 4 + lr) ^ (lc & 7)) * 8)];
            }
            #pragma unroll
            for (int mi = 0; mi < 4; ++mi)
                #pragma unroll
                for (int ni = 0; ni < 4; ++ni)
                    acc[mi][ni] = __builtin_amdgcn_mfma_f32_16x16x32_bf16(
                        af[mi], bfr[ni], acc[mi][ni], 0, 0, 0);
        }
    }

    #pragma unroll
    for (int mi = 0; mi < 4; ++mi) {
        #pragma unroll
        for (int ni = 0; ni < 4; ++ni) {
            int col = n0 + wn * 64 + ni * 16 + lc;
            float bv = bias[col];
            if (MODE == 1) {
                int sec = col >> 10, rem = col & 1023;
                int h = rem >> 6, d = rem & 63;
                int row0 = m0 + wm * 64 + mi * 16 + lr * 4;
                int b = row0 >> 11, s0 = row0 & 2047;
                long idxSD = ((long)((b << 4) + h) * 2048 + s0) * 64 + d;
                if (sec == 0) {
                    #pragma unroll
                    for (int i = 0; i < 4; ++i) {
                        float val = acc[mi][ni][i] + bv;
                        // bake attn scale 1/8 and log2(e) for exp2-domain softmax
                        qbf[idxSD + (long)i * 64] = f2bf(val * 0.1803368801111244f);
                    }
                } else if (sec == 1) {
                    #pragma unroll
                    for (int i = 0; i < 4; ++i) {
                        float val = acc[mi][ni][i] + bv;
                        kout[idxSD + (long)i * 64] = val;
                        kbf[idxSD + (long)i * 64] = f2bf(val);
                    }
                } else {
                    s16x4 pk;
                    #pragma unroll
                    for (int i = 0; i < 4; ++i) {
                        float val = acc[mi][ni][i] + bv;
                        vout[idxSD + (long)i * 64] = val;
                        pk[i] = f2bf(val);
                    }
                    // transposed bf16 copy [B,H,D,S]: 8B packed store
                    *(s16x4*)&vbfT[((long)((b << 4) + h) * 64 + d) * 2048 + s0] = pk;
                }
            } else {
                #pragma unroll
                for (int i = 0; i < 4; ++i) {
                    int row = m0 + wm * 64 + mi * 16 + lr * 4 + i;
                    outf[(long)row * N + col] = acc[mi][ni][i] + bv;
                }
            }
        }
    }
}

// ---------------- flash attention (round-16, unchanged) ----------------
__global__ __launch_bounds__(256, 2) void attn_kernel(const short* __restrict__ qbf,
                                                      const short* __restrict__ kbf,
                                                      const short* __restrict__ vbfT,
                                                      short* __restrict__ obf) {
    const int bid = blockIdx.x;
    const int xcd = bid & 7, r = bid >> 3;      // 64 slots per XCD
    const int head_local = r & 3, q16 = r >> 2; // q16 in 0..15
    const int qt = (q16 < 8) ? (q16 + 8) : (15 - q16);  // slot r and r+32 sum to 34 steps
    const int bh = xcd * 4 + head_local;
    const int tid = threadIdx.x;
    const int wv = tid >> 6, l = tid & 63;      // wv in 0..3
    const int h = l >> 5;                        // lane half
    const int l8 = l & 7;
    const int q0 = qt * 128 + wv * 32;           // this wave's 32-q strip
    const int qlane = q0 + (l & 31);
    const long baseSD = (long)bh * 2048 * 64;   // q,k: [S][64]
    const long baseDS = (long)bh * 64 * 2048;   // vT:  [64][S]

    __shared__ __align__(16) short Ks[2][64 * 64];  // swizzled K tile   (8 KB x2)
    __shared__ __align__(16) short Vs[2][64 * 64];  // swizzled V^T tile (8 KB x2)

    const int sSub = l >> 3;
    const int sChunk = (l & 7) ^ sSub;
    auto stage = [&](int kt, int nb) {
        const int k0 = kt * 64;
        const int r0 = wv * 16 + sSub;
        gload_lds16(kbf + baseSD + (long)(k0 + r0) * 64 + sChunk * 8,
                    &Ks[nb][(wv * 16) * 64]);
        gload_lds16(kbf + baseSD + (long)(k0 + r0 + 8) * 64 + sChunk * 8,
                    &Ks[nb][(wv * 16 + 8) * 64]);
        gload_lds16(vbfT + baseDS + (long)r0 * 2048 + k0 + sChunk * 8,
                    &Vs[nb][(wv * 16) * 64]);
        gload_lds16(vbfT + baseDS + (long)(r0 + 8) * 2048 + k0 + sChunk * 8,
                    &Vs[nb][(wv * 16 + 8) * 64]);
    };

    // Q fragments (B-operand, 32x32x16): lane holds col q = qlane, kdim d = dd*16 + h*8 + j
    s16x8 qf[4];
    #pragma unroll
    for (int dd = 0; dd < 4; ++dd)
        qf[dd] = *(const s16x8*)&qbf[baseSD + (long)qlane * 64 + dd * 16 + h * 8];

    f32x4 lacc = {};                   // 4 independent partial-sum accumulators
    f32x16 O[2] = {};                  // O^T: O[dt2][rr] = O[d = dt2*32+(rr&3)+8*(rr>>2)+4h][qlane]

    const int nkt = 2 * qt + 2;        // k-tiles covering rows 0..qt*128+127

    stage(0, 0);
    __syncthreads();                   // drains vmcnt -> buf0 ready
    int cur = 0;

    for (int kt = 0; kt < nkt; ++kt) {
        const int k0 = kt * 64;
        if (kt + 1 < nkt) stage(kt + 1, cur ^ 1);

        if (k0 <= q0 + 31) {           // strip has unmasked keys in this tile
            const short* Kb = Ks[cur];
            const short* Vb = Vs[cur];
            #pragma unroll
            for (int kk2 = 0; kk2 < 2; ++kk2) {
                // QK: S^T[32k x 32q] accumulated over d
                f32x16 z = {};
                #pragma unroll
                for (int dd = 0; dd < 4; ++dd) {
                    s16x8 kf = *(const s16x8*)&Kb[(kk2 * 32 + (l & 31)) * 64 +
                                                  (((2 * dd + h) ^ l8) * 8)];
                    z = __builtin_amdgcn_mfma_f32_32x32x16_bf16(kf, qf[dd], z, 0, 0, 0);
                }
                // causal mask: k = k0 + kk2*32 + (rr&3)+8*(rr>>2)+4h, q = qlane
                if (k0 + 63 > q0) {
                    #pragma unroll
                    for (int rr = 0; rr < 16; ++rr) {
                        int kpos = k0 + kk2 * 32 + (rr & 3) + 8 * (rr >> 2) + 4 * h;
                        if (kpos > qlane) z[rr] = -INFINITY;
                    }
                }
                // static softmax: p = exp2(s'); exp2(-inf) = 0 handles the mask
                float p[16];
                #pragma unroll
                for (int rr = 0; rr < 16; ++rr) {
                    p[rr] = __builtin_amdgcn_exp2f(z[rr]);
                    lacc[rr & 3] += p[rr];
                }
                // PV per 16-k fragment f (k base fb = kk2*32 + f*16), pi-permuted kdim:
                //   B = packed own p[f*8..f*8+7] via v_cvt_pk_bf16_f32 (builtin, RNE);
                //   A = V^T rows, two b64 at k = fb+4h and fb+8+4h.
                #pragma unroll
                for (int f = 0; f < 2; ++f) {
                    union { __hip_bfloat162 b2[4]; s16x8 v; } pk;
                    #pragma unroll
                    for (int j = 0; j < 4; ++j)
                        pk.b2[j] = __float22bfloat162_rn(
                            make_float2(p[f * 8 + 2 * j], p[f * 8 + 2 * j + 1]));
                    const int c0 = kk2 * 4 + f * 2;       // logical chunk of fb
                    #pragma unroll
                    for (int dt2 = 0; dt2 < 2; ++dt2) {
                        const short* vr = &Vb[(dt2 * 32 + (l & 31)) * 64];
                        s16x8 vf;
                        *(s16x4*)&vf = *(const s16x4*)&vr[(c0 ^ l8) * 8 + 4 * h];
                        *(((s16x4*)&vf) + 1) = *(const s16x4*)&vr[((c0 + 1) ^ l8) * 8 + 4 * h];
                        O[dt2] = __builtin_amdgcn_mfma_f32_32x32x16_bf16(vf, pk.v,
                                                                         O[dt2], 0, 0, 0);
                    }
                }
            }
        }
        __syncthreads();               // all done with buf[cur]; stage(kt+1) drained
        cur ^= 1;
    }

    // epilogue: combine 4 partials, merge lane halves (1 shuffle), O /= lsum; 8B stores
    float lsum = (lacc[0] + lacc[1]) + (lacc[2] + lacc[3]);
    lsum += __shfl_xor(lsum, 32);
    const int b = bh >> 4, hd = bh & 15;
    float inv = 1.0f / lsum;
    #pragma unroll
    for (int dt2 = 0; dt2 < 2; ++dt2) {
        #pragma unroll
        for (int g = 0; g < 4; ++g) {
            s16x4 o;
            #pragma unroll
            for (int i = 0; i < 4; ++i) o[i] = f2bf(O[dt2][g * 4 + i] * inv);
            const int d = dt2 * 32 + 8 * g + 4 * h;
            *(s16x4*)&obf[(long)(b * 2048 + qlane) * 1024 + hd * 64 + d] = o;
        }
    }
}

// ---------------- launch ----------------

extern "C" void kernel_launch(void* const* d_in, const int* in_sizes, int n_in,
                              void* d_out, int out_size, void* d_ws, size_t ws_size,
                              hipStream_t stream) {
    const float* x = (const float*)d_in[0];
    const float* qkv_w = (const float*)d_in[1];
    const float* qkv_b = (const float*)d_in[2];
    const float* proj_w = (const float*)d_in[3];
    const float* proj_b = (const float*)d_in[4];

    float* out = (float*)d_out;
    float* kout = out + 4194304;
    float* vout = out + 8388608;

    short* x_bf = (short*)d_ws;           // 4194304 shorts
    short* wT1 = x_bf + 4194304;          // 3145728
    short* wT2 = wT1 + 3145728;           // 1048576
    short* q_bf = wT2 + 1048576;          // 4194304
    short* k_bf = q_bf + 4194304;         // 4194304
    short* vT_bf = k_bf + 4194304;        // 4194304 ([B,H,D,S])
    short* o_bf = x_bf;                   // alias: x_bf dead after GEMM1

    fused_prepass<<<6144, 256, 0, stream>>>(x, x_bf, qkv_w, wT1, proj_w, wT2);

    gemm_bf16<1><<<768, 256, 0, stream>>>(x_bf, wT1, qkv_b, 4096, 3072, 1024,
                                          nullptr, q_bf, k_bf, vT_bf, kout, vout);

    attn_kernel<<<512, 256, 0, stream>>>(q_bf, k_bf, vT_bf, o_bf);

    gemm_bf16<2><<<256, 256, 0, stream>>>(o_bf, wT2, proj_b, 4096, 1024, 1024,
                                          out, nullptr, nullptr, nullptr, nullptr, nullptr);
}

// Round 19
// 104.461 us; speedup vs baseline: 1.4503x; 1.0502x over previous
//
#include <hip/hip_runtime.h>
#include <hip/hip_bf16.h>

// Shapes (fixed): B=2, S=2048, E=1024, H=16, D=64
// d_out: out[4194304] fp32 | k[4194304] fp32 [B,H,S,D] | v[4194304] fp32 [B,H,S,D]
// ws: x_bf | wT1 | wT2 | q_bf | k_bf | vT_bf ; o_bf aliases x_bf.

typedef __attribute__((ext_vector_type(4))) float f32x4;
typedef __attribute__((ext_vector_type(16))) float f32x16;
typedef __attribute__((ext_vector_type(8))) short s16x8;
typedef __attribute__((ext_vector_type(4))) short s16x4;

__device__ __forceinline__ short f2bf(float f) {
    union { float f; unsigned u; } x{f};
    unsigned r = x.u + 0x7fff + ((x.u >> 16) & 1);
    return (short)(r >> 16);
}

__device__ __forceinline__ void gload_lds16(const void* g, void* l) {
    __builtin_amdgcn_global_load_lds(
        (const __attribute__((address_space(1))) void*)g,
        (__attribute__((address_space(3))) void*)l, 16, 0, 0);
}

// ---------------- fused pre-pass (1 launch) ----------------
// blocks [0,2048):        x fp32 -> x_bf (8 elems/thread)
// blocks [2048,5120):     qkv_w [1024][3072] -> wT1 [3072][1024] bf16
// blocks [5120,6144):     proj_w [1024][1024] -> wT2 [1024][1024] bf16
__global__ __launch_bounds__(256) void fused_prepass(const float* __restrict__ x,
                                                     short* __restrict__ x_bf,
                                                     const float* __restrict__ qkv_w,
                                                     short* __restrict__ wT1,
                                                     const float* __restrict__ proj_w,
                                                     short* __restrict__ wT2) {
    __shared__ float tile[32][33];
    const int bid = blockIdx.x, tid = threadIdx.x;
    if (bid < 2048) {
        int i = (bid * 256 + tid) * 8;
        f32x4 a = *(const f32x4*)&x[i];
        f32x4 b = *(const f32x4*)&x[i + 4];
        s16x8 o;
        #pragma unroll
        for (int j = 0; j < 4; ++j) o[j] = f2bf(a[j]);
        #pragma unroll
        for (int j = 0; j < 4; ++j) o[j + 4] = f2bf(b[j]);
        *(s16x8*)&x_bf[i] = o;
        return;
    }
    const float* in;
    short* out;
    int K = 1024, N, n0, k0;
    if (bid < 5120) {
        int blk = bid - 2048;
        in = qkv_w; out = wT1; N = 3072;
        n0 = (blk % 96) * 32; k0 = (blk / 96) * 32;
    } else {
        int blk = bid - 5120;
        in = proj_w; out = wT2; N = 1024;
        n0 = (blk & 31) * 32; k0 = (blk >> 5) * 32;
    }
    const int tx = tid & 31, ty = tid >> 5;  // 32 x 8
    #pragma unroll
    for (int r = 0; r < 4; ++r)
        tile[ty + r * 8][tx] = in[(long)(k0 + ty + r * 8) * N + n0 + tx];
    __syncthreads();
    #pragma unroll
    for (int r = 0; r < 4; ++r)
        out[(long)(n0 + ty + r * 8) * K + k0 + tx] = f2bf(tile[tx][ty + r * 8]);
}

// ---------------- GEMM (128x128 tile, BK=64, XOR-swizzled LDS, XCD patch swizzle) -------
// (round-17, unchanged — GEMM1 dropped out of top-5 at this config)
template <int MODE>
__global__ __launch_bounds__(256) void gemm_bf16(
    const short* __restrict__ A, const short* __restrict__ Bt,
    const float* __restrict__ bias, int M, int N, int K,
    float* __restrict__ outf,
    short* __restrict__ qbf, short* __restrict__ kbf, short* __restrict__ vbfT,
    float* __restrict__ kout, float* __restrict__ vout) {
    __shared__ __align__(16) short As[128 * 64];
    __shared__ __align__(16) short Bs[128 * 64];
    const int tid = threadIdx.x;
    const int l = tid & 63, w = tid >> 6;
    const int lr = l >> 4, lc = l & 15;
    const int wm = w >> 1, wn = w & 1;
    const int bid = blockIdx.x;
    const int xcd = bid & 7, s = bid >> 3;
    int bx, by;
    if (MODE == 1) { bx = (xcd & 1) * 12 + s % 12; by = (xcd >> 1) * 8 + s / 12; }
    else           { bx = (xcd & 1) * 4 + (s & 3); by = (xcd >> 1) * 8 + (s >> 2); }
    const int m0 = by * 128, n0 = bx * 128;

    f32x4 acc[4][4] = {};

    for (int kb = 0; kb < K; kb += 64) {
        __syncthreads();
        #pragma unroll
        for (int j = 0; j < 4; ++j) {
            const int c = tid + 256 * j;
            const int row = c >> 3;
            const int lseg = (c & 7) ^ (row & 7);
            gload_lds16(A + (long)(m0 + row) * K + kb + lseg * 8, As + c * 8);
            gload_lds16(Bt + (long)(n0 + row) * K + kb + lseg * 8, Bs + c * 8);
        }
        __syncthreads();
        #pragma unroll
        for (int kh = 0; kh < 2; ++kh) {
            s16x8 af[4], bfr[4];
            #pragma unroll
            for (int mi = 0; mi < 4; ++mi) {
                const int row = wm * 64 + mi * 16 + lc;
                af[mi] = *(const s16x8*)&As[row * 64 + (((kh * 4 + lr) ^ (lc & 7)) * 8)];
            }
            #pragma unroll
            for (int ni = 0; ni < 4; ++ni) {
                const int row = wn * 64 + ni * 16 + lc;
                bfr[ni] = *(const s16x8*)&Bs[row * 64 + (((kh * 4 + lr) ^ (lc & 7)) * 8)];
            }
            #pragma unroll
            for (int mi = 0; mi < 4; ++mi)
                #pragma unroll
                for (int ni = 0; ni < 4; ++ni)
                    acc[mi][ni] = __builtin_amdgcn_mfma_f32_16x16x32_bf16(
                        af[mi], bfr[ni], acc[mi][ni], 0, 0, 0);
        }
    }

    #pragma unroll
    for (int mi = 0; mi < 4; ++mi) {
        #pragma unroll
        for (int ni = 0; ni < 4; ++ni) {
            int col = n0 + wn * 64 + ni * 16 + lc;
            float bv = bias[col];
            if (MODE == 1) {
                int sec = col >> 10, rem = col & 1023;
                int h = rem >> 6, d = rem & 63;
                int row0 = m0 + wm * 64 + mi * 16 + lr * 4;
                int b = row0 >> 11, s0 = row0 & 2047;
                long idxSD = ((long)((b << 4) + h) * 2048 + s0) * 64 + d;
                if (sec == 0) {
                    #pragma unroll
                    for (int i = 0; i < 4; ++i) {
                        float val = acc[mi][ni][i] + bv;
                        // bake attn scale 1/8 and log2(e) for exp2-domain softmax
                        qbf[idxSD + (long)i * 64] = f2bf(val * 0.1803368801111244f);
                    }
                } else if (sec == 1) {
                    #pragma unroll
                    for (int i = 0; i < 4; ++i) {
                        float val = acc[mi][ni][i] + bv;
                        kout[idxSD + (long)i * 64] = val;
                        kbf[idxSD + (long)i * 64] = f2bf(val);
                    }
                } else {
                    s16x4 pk;
                    #pragma unroll
                    for (int i = 0; i < 4; ++i) {
                        float val = acc[mi][ni][i] + bv;
                        vout[idxSD + (long)i * 64] = val;
                        pk[i] = f2bf(val);
                    }
                    *(s16x4*)&vbfT[((long)((b << 4) + h) * 64 + d) * 2048 + s0] = pk;
                }
            } else {
                #pragma unroll
                for (int i = 0; i < 4; ++i) {
                    int row = m0 + wm * 64 + mi * 16 + lr * 4 + i;
                    outf[(long)row * N + col] = acc[mi][ni][i] + bv;
                }
            }
        }
    }
}

// ---------------- flash attention (8 waves: k-split pairs + ADD merge) ----------------
// grid: 512 blocks = 32 bh x 16 q-tiles of 128 rows; 512 threads (8 waves).
// Wave wv: strip = wv&3 (32 q-rows at q0 = qt*128+strip*32), kh = wv>>2 (key half).
// Per 64-key step each wave computes ONLY its 32-key half (kk2 = kh): per-wave serial
// chain halves (4 QK + 4 PV MFMAs, 16 exp2) while waves/CU double (16 = 4/SIMD) -> the
// latency-bound chain finally has TLP to hide under. STATIC softmax makes the k-split
// merge a pure ADD (O and lsum are sums over k — no max/rescale bookkeeping):
// kh=1 publishes O+lsum to LDS once at the end; kh=0 adds and stores.
// Staging (all 8 waves): K [64k][64d] + V^T [64d][64k] once per step, global_load_lds w16,
// double-buffered, chunk XOR-swizzle both-sides (phys seg = logical seg ^ (row&7)).
// 32x32x16 MFMAs; C-layout col q = lane&31, row = (r&3)+8*(r>>2)+4*(lane>>5).
// P in registers via kdim permutation pi (verified r12): B = cvt_pk of own p[8] in order;
// A (V^T) = two ds_read_b64 at k = fb+4h and fb+8+4h.
__global__ __launch_bounds__(512, 4) void attn_kernel(const short* __restrict__ qbf,
                                                      const short* __restrict__ kbf,
                                                      const short* __restrict__ vbfT,
                                                      short* __restrict__ obf) {
    const int bid = blockIdx.x;
    const int xcd = bid & 7, r = bid >> 3;      // 64 slots per XCD
    const int head_local = r & 3, q16 = r >> 2; // q16 in 0..15
    const int qt = (q16 < 8) ? (q16 + 8) : (15 - q16);  // CU slot-pair qt sums = 15
    const int bh = xcd * 4 + head_local;
    const int tid = threadIdx.x;
    const int wv = tid >> 6, l = tid & 63;      // wv in 0..7
    const int strip = wv & 3, kh = wv >> 2;     // q-strip, key-half
    const int h = l >> 5;                        // lane half
    const int l8 = l & 7;
    const int q0 = qt * 128 + strip * 32;        // this wave's 32-q strip
    const int qlane = q0 + (l & 31);
    const long baseSD = (long)bh * 2048 * 64;   // q,k: [S][64]
    const long baseDS = (long)bh * 64 * 2048;   // vT:  [64][S]

    __shared__ __align__(16) short Ks[2][64 * 64];  // swizzled K tile   (8 KB x2)
    __shared__ __align__(16) short Vs[2][64 * 64];  // swizzled V^T tile (8 KB x2)
    __shared__ __align__(16) float MG[4][64][36];   // merge: O[32] | lsum (36 KB, one-time)

    // staging: wave wv stages rows wv*8..wv*8+7 of K and V^T (1 gload each);
    // lane l -> row base+(l>>3), phys chunk l&7 holds logical chunk (l&7)^(l>>3).
    const int sSub = l >> 3;
    const int sChunk = (l & 7) ^ sSub;
    auto stage = [&](int kt, int nb) {
        const int k0 = kt * 64;
        const int r0 = wv * 8 + sSub;
        gload_lds16(kbf + baseSD + (long)(k0 + r0) * 64 + sChunk * 8,
                    &Ks[nb][(wv * 8) * 64]);
        gload_lds16(vbfT + baseDS + (long)r0 * 2048 + k0 + sChunk * 8,
                    &Vs[nb][(wv * 8) * 64]);
    };

    // Q fragments (B-operand, 32x32x16): lane holds col q = qlane, kdim d = dd*16 + h*8 + j
    s16x8 qf[4];
    #pragma unroll
    for (int dd = 0; dd < 4; ++dd)
        qf[dd] = *(const s16x8*)&qbf[baseSD + (long)qlane * 64 + dd * 16 + h * 8];

    f32x4 lacc = {};                   // 4 independent partial-sum accumulators
    f32x16 O[2] = {};                  // O^T: O[dt2][rr] = O[d = dt2*32+(rr&3)+8*(rr>>2)+4h][qlane]

    const int nkt = 2 * qt + 2;        // k-tiles covering rows 0..qt*128+127

    stage(0, 0);
    __syncthreads();                   // drains vmcnt -> buf0 ready
    int cur = 0;

    for (int kt = 0; kt < nkt; ++kt) {
        if (kt + 1 < nkt) stage(kt + 1, cur ^ 1);
        const int kbase = kt * 64 + kh * 32;   // this wave's 32-key half

        if (kbase <= q0 + 31) {        // half has unmasked keys for this strip
            const short* Kb = Ks[cur];
            const short* Vb = Vs[cur];
            // QK: S^T[32k x 32q] accumulated over d (keys kbase..kbase+31)
            f32x16 z = {};
            #pragma unroll
            for (int dd = 0; dd < 4; ++dd) {
                s16x8 kf = *(const s16x8*)&Kb[(kh * 32 + (l & 31)) * 64 +
                                              (((2 * dd + h) ^ l8) * 8)];
                z = __builtin_amdgcn_mfma_f32_32x32x16_bf16(kf, qf[dd], z, 0, 0, 0);
            }
            // causal mask: k = kbase + (rr&3)+8*(rr>>2)+4h, q = qlane
            if (kbase + 31 > q0) {
                #pragma unroll
                for (int rr = 0; rr < 16; ++rr) {
                    int kpos = kbase + (rr & 3) + 8 * (rr >> 2) + 4 * h;
                    if (kpos > qlane) z[rr] = -INFINITY;
                }
            }
            // static softmax: p = exp2(s'); exp2(-inf) = 0 handles the mask
            float p[16];
            #pragma unroll
            for (int rr = 0; rr < 16; ++rr) {
                p[rr] = __builtin_amdgcn_exp2f(z[rr]);
                lacc[rr & 3] += p[rr];
            }
            // PV per 16-k fragment f (k base fb = kh*32 + f*16), pi-permuted kdim:
            //   B = packed own p[f*8..f*8+7] via v_cvt_pk_bf16_f32 (builtin, RNE);
            //   A = V^T rows, two b64 at k = fb+4h and fb+8+4h.
            #pragma unroll
            for (int f = 0; f < 2; ++f) {
                union { __hip_bfloat162 b2[4]; s16x8 v; } pk;
                #pragma unroll
                for (int j = 0; j < 4; ++j)
                    pk.b2[j] = __float22bfloat162_rn(
                        make_float2(p[f * 8 + 2 * j], p[f * 8 + 2 * j + 1]));
                const int c0 = kh * 4 + f * 2;        // logical chunk of fb
                #pragma unroll
                for (int dt2 = 0; dt2 < 2; ++dt2) {
                    const short* vr = &Vb[(dt2 * 32 + (l & 31)) * 64];
                    s16x8 vf;
                    *(s16x4*)&vf = *(const s16x4*)&vr[(c0 ^ l8) * 8 + 4 * h];
                    *(((s16x4*)&vf) + 1) = *(const s16x4*)&vr[((c0 + 1) ^ l8) * 8 + 4 * h];
                    O[dt2] = __builtin_amdgcn_mfma_f32_32x32x16_bf16(vf, pk.v,
                                                                     O[dt2], 0, 0, 0);
                }
            }
        }
        __syncthreads();               // all done with buf[cur]; stage(kt+1) drained
        cur ^= 1;
    }

    // ---- k-half merge (pure ADD: static softmax => O, lsum are sums over k) ----
    float lsum = (lacc[0] + lacc[1]) + (lacc[2] + lacc[3]);
    if (kh == 1) {
        float* row = &MG[strip][l][0];
        #pragma unroll
        for (int dt2 = 0; dt2 < 2; ++dt2)
            #pragma unroll
            for (int rr = 0; rr < 16; ++rr)
                row[dt2 * 16 + rr] = O[dt2][rr];
        row[32] = lsum;
    }
    __syncthreads();
    if (kh == 0) {
        const float* row = &MG[strip][l][0];
        lsum += row[32];
        lsum += __shfl_xor(lsum, 32);  // combine lane halves (complementary k offsets)
        const int b = bh >> 4, hd = bh & 15;
        float inv = 1.0f / lsum;
        #pragma unroll
        for (int dt2 = 0; dt2 < 2; ++dt2) {
            #pragma unroll
            for (int g = 0; g < 4; ++g) {
                s16x4 o;
                #pragma unroll
                for (int i = 0; i < 4; ++i)
                    o[i] = f2bf((O[dt2][g * 4 + i] + row[dt2 * 16 + g * 4 + i]) * inv);
                const int d = dt2 * 32 + 8 * g + 4 * h;
                *(s16x4*)&obf[(long)(b * 2048 + qlane) * 1024 + hd * 64 + d] = o;
            }
        }
    }
}

// ---------------- launch ----------------

extern "C" void kernel_launch(void* const* d_in, const int* in_sizes, int n_in,
                              void* d_out, int out_size, void* d_ws, size_t ws_size,
                              hipStream_t stream) {
    const float* x = (const float*)d_in[0];
    const float* qkv_w = (const float*)d_in[1];
    const float* qkv_b = (const float*)d_in[2];
    const float* proj_w = (const float*)d_in[3];
    const float* proj_b = (const float*)d_in[4];

    float* out = (float*)d_out;
    float* kout = out + 4194304;
    float* vout = out + 8388608;

    short* x_bf = (short*)d_ws;           // 4194304 shorts
    short* wT1 = x_bf + 4194304;          // 3145728
    short* wT2 = wT1 + 3145728;           // 1048576
    short* q_bf = wT2 + 1048576;          // 4194304
    short* k_bf = q_bf + 4194304;         // 4194304
    short* vT_bf = k_bf + 4194304;        // 4194304 ([B,H,D,S])
    short* o_bf = x_bf;                   // alias: x_bf dead after GEMM1

    fused_prepass<<<6144, 256, 0, stream>>>(x, x_bf, qkv_w, wT1, proj_w, wT2);

    gemm_bf16<1><<<768, 256, 0, stream>>>(x_bf, wT1, qkv_b, 4096, 3072, 1024,
                                          nullptr, q_bf, k_bf, vT_bf, kout, vout);

    attn_kernel<<<512, 512, 0, stream>>>(q_bf, k_bf, vT_bf, o_bf);

    gemm_bf16<2><<<256, 256, 0, stream>>>(o_bf, wT2, proj_b, 4096, 1024, 1024,
                                          out, nullptr, nullptr, nullptr, nullptr, nullptr);
}